// Round 1
// baseline (401.481 us; speedup 1.0000x reference)
//
#include <hip/hip_runtime.h>
#include <math.h>

#define NRAYS 1024
#define NSAMP 512
#define GRIDN 300
#define POS_ELEMS (GRIDN*GRIDN)
#define PLANE_ELEMS (16*POS_ELEMS)
#define XSTR 156   // LDS row stride for 150-col X / W1 (odd quad-offset -> conflict-spread, 16B aligned)
#define HSTR 132   // LDS row stride for 128-col H / W2

__device__ __forceinline__ float clampf(float x, float a, float b){ return fminf(fmaxf(x,a),b); }

// ---------------------------------------------------------------- transpose
// (16,300,300) channel-major -> (300,300,16) channel-last; same for lines.
struct TPtrs {
    const float* psrc[6]; float* pdst[6];
    const float* lsrc[6]; float* ldst[6];
};

__global__ __launch_bounds__(256) void k_transpose(TPtrs tp) {
    int by  = blockIdx.y;
    int pos = blockIdx.x * 256 + threadIdx.x;
    if (pos < POS_ELEMS) {
        const float* src = tp.psrc[by];
        float v[16];
        #pragma unroll
        for (int c = 0; c < 16; c++) v[c] = src[c * POS_ELEMS + pos];
        float4* dst = (float4*)(tp.pdst[by] + (size_t)pos * 16);
        dst[0] = make_float4(v[0],v[1],v[2],v[3]);
        dst[1] = make_float4(v[4],v[5],v[6],v[7]);
        dst[2] = make_float4(v[8],v[9],v[10],v[11]);
        dst[3] = make_float4(v[12],v[13],v[14],v[15]);
    }
    if (pos < GRIDN) {   // first two blocks handle the 300-entry line
        const float* ls = tp.lsrc[by];
        float*       ld = tp.ldst[by];
        #pragma unroll
        for (int c = 0; c < 16; c++) ld[pos * 16 + c] = ls[c * GRIDN + pos];
    }
}

// ---------------------------------------------------------------- density + weights
__global__ __launch_bounds__(512) void k_density(
    const float* __restrict__ ro, const float* __restrict__ rd,
    const float* __restrict__ dpT0, const float* __restrict__ dpT1, const float* __restrict__ dpT2,
    const float* __restrict__ dlT0, const float* __restrict__ dlT1, const float* __restrict__ dlT2,
    float* __restrict__ weights, float* __restrict__ acc_out, float* __restrict__ depth_out,
    int* __restrict__ list, int* __restrict__ counter)
{
    const float STEPF = (3.0f/299.0f)*0.5f;
    int r = blockIdx.x;
    int s = threadIdx.x;

    float o0=ro[r*3+0], o1=ro[r*3+1], o2=ro[r*3+2];
    float d0=rd[r*3+0], d1=rd[r*3+1], d2=rd[r*3+2];

    float t_min = -1e30f;
    {
        float v0=(d0==0.f)?1e-6f:d0, v1=(d1==0.f)?1e-6f:d1, v2=(d2==0.f)?1e-6f:d2;
        float a,b;
        a=(1.5f-o0)/v0; b=(-1.5f-o0)/v0; t_min=fmaxf(t_min,fminf(a,b));
        a=(1.5f-o1)/v1; b=(-1.5f-o1)/v1; t_min=fmaxf(t_min,fminf(a,b));
        a=(1.5f-o2)/v2; b=(-1.5f-o2)/v2; t_min=fmaxf(t_min,fminf(a,b));
        t_min = clampf(t_min, 2.0f, 6.0f);
    }
    float z  = t_min + STEPF * (float)s;
    float p0 = o0 + d0*z, p1 = o1 + d1*z, p2 = o2 + d2*z;
    bool valid = (p0>=-1.5f)&&(p0<=1.5f)&&(p1>=-1.5f)&&(p1<=1.5f)&&(p2>=-1.5f)&&(p2<=1.5f);

    float sig = 0.f;
    if (valid) {
        float xn[3] = { (p0+1.5f)*(2.0f/3.0f)-1.0f,
                        (p1+1.5f)*(2.0f/3.0f)-1.0f,
                        (p2+1.5f)*(2.0f/3.0f)-1.0f };
        const float* dpT[3] = {dpT0,dpT1,dpT2};
        const float* dlT[3] = {dlT0,dlT1,dlT2};
        const int M0[3]={0,0,1}, M1[3]={1,2,2}, V[3]={2,1,0};
        float sf = 0.f;
        #pragma unroll
        for (int i=0;i<3;i++) {
            float fx = clampf((xn[M0[i]]*0.5f+0.5f)*299.f, 0.f, 299.f);
            float fy = clampf((xn[M1[i]]*0.5f+0.5f)*299.f, 0.f, 299.f);
            float ft = clampf((xn[V[i]] *0.5f+0.5f)*299.f, 0.f, 299.f);
            int x0=min((int)fx,298), y0=min((int)fy,298), i0=min((int)ft,298);
            float wx=fx-(float)x0, wy=fy-(float)y0, wt=ft-(float)i0;
            const float4* row0 = (const float4*)(dpT[i] + (size_t)(y0*GRIDN+x0)*16);
            const float4* row1 = (const float4*)(dpT[i] + (size_t)((y0+1)*GRIDN+x0)*16);
            const float4* ln   = (const float4*)(dlT[i] + (size_t)i0*16);
            #pragma unroll
            for (int q=0;q<4;q++) {
                float4 a00=row0[q], a01=row0[q+4], a10=row1[q], a11=row1[q+4];
                float4 l0=ln[q],   l1=ln[q+4];
                float bx = (a00.x*(1.f-wx)+a01.x*wx)*(1.f-wy) + (a10.x*(1.f-wx)+a11.x*wx)*wy;
                float by = (a00.y*(1.f-wx)+a01.y*wx)*(1.f-wy) + (a10.y*(1.f-wx)+a11.y*wx)*wy;
                float bz = (a00.z*(1.f-wx)+a01.z*wx)*(1.f-wy) + (a10.z*(1.f-wx)+a11.z*wx)*wy;
                float bw = (a00.w*(1.f-wx)+a01.w*wx)*(1.f-wy) + (a10.w*(1.f-wx)+a11.w*wx)*wy;
                float lx = l0.x*(1.f-wt)+l1.x*wt;
                float ly = l0.y*(1.f-wt)+l1.y*wt;
                float lz = l0.z*(1.f-wt)+l1.z*wt;
                float lw = l0.w*(1.f-wt)+l1.w*wt;
                sf += bx*lx + by*ly + bz*lz + bw*lw;
            }
        }
        float xs = sf - 10.0f;                       // DENSITY_SHIFT
        sig = (xs > 20.f) ? xs : log1pf(expf(xs));   // softplus
    }
    float alpha = (s < NSAMP-1) ? (1.f - expf(-sig * (STEPF*25.0f))) : 0.f;

    __shared__ float sm[NSAMP];
    sm[s] = (1.f - alpha) + 1e-10f;
    __syncthreads();
    #pragma unroll
    for (int off=1; off<NSAMP; off<<=1) {            // inclusive multiplicative scan
        float v  = sm[s];
        float pr = (s>=off) ? sm[s-off] : 1.f;
        __syncthreads();
        sm[s] = v*pr;
        __syncthreads();
    }
    float T = (s==0) ? 1.f : sm[s-1];
    float w = alpha * T;
    weights[r*NSAMP + s] = w;

    __syncthreads();
    sm[s] = w;
    __syncthreads();
    for (int off=NSAMP/2; off>0; off>>=1) { if (s<off) sm[s]+=sm[s+off]; __syncthreads(); }
    float wsum = sm[0];
    __syncthreads();
    sm[s] = w*z;
    __syncthreads();
    for (int off=NSAMP/2; off>0; off>>=1) { if (s<off) sm[s]+=sm[s+off]; __syncthreads(); }
    if (s==0) { acc_out[r] = wsum; depth_out[r] = sm[0]; }

    // wave-aggregated compaction of samples with weight > W_THRES
    bool act = (w > 1e-4f);
    unsigned long long m = __ballot(act);
    int lane = s & 63;
    int cnt  = __popcll(m);
    if (cnt) {
        int base = 0;
        if (lane==0) base = atomicAdd(counter, cnt);
        base = __shfl(base, 0);
        if (act) {
            int pofs = __popcll(m & ((1ull<<lane)-1ull));
            list[base + pofs] = (r<<9) | s;
        }
    }
}

// ---------------------------------------------------------------- masked appearance + MLP
__global__ __launch_bounds__(256) void k_mlp(
    const float* __restrict__ ro, const float* __restrict__ rd,
    const float* __restrict__ apT0, const float* __restrict__ apT1, const float* __restrict__ apT2,
    const float* __restrict__ alT0, const float* __restrict__ alT1, const float* __restrict__ alT2,
    const float* __restrict__ basis_w, const float* __restrict__ w1, const float* __restrict__ b1,
    const float* __restrict__ w2, const float* __restrict__ b2,
    const float* __restrict__ w3, const float* __restrict__ b3,
    const float* __restrict__ weights, const int* __restrict__ list, const int* __restrict__ counter,
    float* __restrict__ rgbacc)
{
    __shared__ float Xs[64*XSTR];      // mlp_in (150+2 pad), later H2 (stride HSTR)
    __shared__ float Ws[128*XSTR];     // W1 (stride XSTR) then W2 (stride HSTR)
    __shared__ float Hs[64*HSTR];      // coefs (stride 48) then H1 (stride HSTR)
    __shared__ float g_xn[64][3];
    __shared__ float g_view[64][3];
    __shared__ float g_w[64];
    __shared__ int   g_ray[64];

    const float STEPF = (3.0f/299.0f)*0.5f;
    int tid = threadIdx.x;
    int count  = *counter;
    int ntiles = (count + 63) >> 6;

    for (int t = blockIdx.x; t < ntiles; t += gridDim.x) {
        // ---- P0: per-sample geometry
        if (tid < 64) {
            int u = tid, idx = (t<<6) + u;
            float wv = 0.f;
            if (idx < count) {
                int sid = list[idx];
                int r = sid >> 9, s = sid & (NSAMP-1);
                float o0=ro[r*3+0], o1=ro[r*3+1], o2=ro[r*3+2];
                float d0=rd[r*3+0], d1=rd[r*3+1], d2=rd[r*3+2];
                float t_min = -1e30f;
                float v0=(d0==0.f)?1e-6f:d0, v1=(d1==0.f)?1e-6f:d1, v2=(d2==0.f)?1e-6f:d2;
                float a,b;
                a=(1.5f-o0)/v0; b=(-1.5f-o0)/v0; t_min=fmaxf(t_min,fminf(a,b));
                a=(1.5f-o1)/v1; b=(-1.5f-o1)/v1; t_min=fmaxf(t_min,fminf(a,b));
                a=(1.5f-o2)/v2; b=(-1.5f-o2)/v2; t_min=fmaxf(t_min,fminf(a,b));
                t_min = clampf(t_min, 2.0f, 6.0f);
                float z = t_min + STEPF*(float)s;
                g_xn[u][0] = ((o0+d0*z)+1.5f)*(2.0f/3.0f)-1.0f;
                g_xn[u][1] = ((o1+d1*z)+1.5f)*(2.0f/3.0f)-1.0f;
                g_xn[u][2] = ((o2+d2*z)+1.5f)*(2.0f/3.0f)-1.0f;
                g_view[u][0]=d0; g_view[u][1]=d1; g_view[u][2]=d2;
                g_ray[u] = r;
                wv = weights[sid];
            } else {
                g_xn[u][0]=g_xn[u][1]=g_xn[u][2]=0.f;
                g_view[u][0]=g_view[u][1]=g_view[u][2]=0.f;
                g_ray[u]=0;
            }
            g_w[u] = wv;
        }
        __syncthreads();

        // ---- P1: 48 appearance coefs per sample -> Hs (stride 48)
        {
            int u = tid >> 2, q = tid & 3;
            const float* apT[3]={apT0,apT1,apT2};
            const float* alT[3]={alT0,alT1,alT2};
            const int M0[3]={0,0,1}, M1[3]={1,2,2}, V[3]={2,1,0};
            #pragma unroll
            for (int i=0;i<3;i++) {
                float fx = clampf((g_xn[u][M0[i]]*0.5f+0.5f)*299.f, 0.f, 299.f);
                float fy = clampf((g_xn[u][M1[i]]*0.5f+0.5f)*299.f, 0.f, 299.f);
                float ft = clampf((g_xn[u][V[i]] *0.5f+0.5f)*299.f, 0.f, 299.f);
                int x0=min((int)fx,298), y0=min((int)fy,298), i0=min((int)ft,298);
                float wx=fx-(float)x0, wy=fy-(float)y0, wt=ft-(float)i0;
                const float4* r0p = (const float4*)(apT[i] + (size_t)(y0*GRIDN+x0)*16) + q;
                const float4* r1p = (const float4*)(apT[i] + (size_t)((y0+1)*GRIDN+x0)*16) + q;
                const float4* lp  = (const float4*)(alT[i] + (size_t)i0*16) + q;
                float4 a00=r0p[0], a01=r0p[4], a10=r1p[0], a11=r1p[4];
                float4 l0=lp[0], l1=lp[4];
                float bx=(a00.x*(1.f-wx)+a01.x*wx)*(1.f-wy)+(a10.x*(1.f-wx)+a11.x*wx)*wy;
                float by=(a00.y*(1.f-wx)+a01.y*wx)*(1.f-wy)+(a10.y*(1.f-wx)+a11.y*wx)*wy;
                float bz=(a00.z*(1.f-wx)+a01.z*wx)*(1.f-wy)+(a10.z*(1.f-wx)+a11.z*wx)*wy;
                float bw=(a00.w*(1.f-wx)+a01.w*wx)*(1.f-wy)+(a10.w*(1.f-wx)+a11.w*wx)*wy;
                float lx=l0.x*(1.f-wt)+l1.x*wt, ly=l0.y*(1.f-wt)+l1.y*wt;
                float lz=l0.z*(1.f-wt)+l1.z*wt, lw=l0.w*(1.f-wt)+l1.w*wt;
                *(float4*)&Hs[u*48 + i*16 + q*4] = make_float4(bx*lx, by*ly, bz*lz, bw*lw);
            }
        }
        __syncthreads();

        // ---- P2: feat = basis_w @ coefs, + posenc -> Xs (stride XSTR)
        {
            int u = tid >> 2, q = tid & 3;
            float* X = Xs + u*XSTR;
            const float* C = Hs + u*48;
            for (int j=q; j<27; j+=4) {
                float f = 0.f;
                const float* bw = basis_w + j*48;
                #pragma unroll
                for (int k=0;k<48;k++) f += bw[k]*C[k];
                X[j] = f;
                X[30+2*j]=sinf(f);  X[31+2*j]=sinf(2.f*f);
                X[84+2*j]=cosf(f);  X[85+2*j]=cosf(2.f*f);
            }
            if (q==3) {
                #pragma unroll
                for (int c=0;c<3;c++) {
                    float v = g_view[u][c];
                    X[27+c]=v;
                    X[138+2*c]=sinf(v); X[139+2*c]=sinf(2.f*v);
                    X[144+2*c]=cosf(v); X[145+2*c]=cosf(2.f*v);
                }
                X[150]=0.f; X[151]=0.f;   // k-pad
            }
        }
        // ---- P3: stage W1 (no sync needed before: Ws idle since loop-end sync)
        for (int idx = tid; idx < 19200; idx += 256) {
            int j = idx / 150, k = idx - j*150;
            Ws[j*XSTR + k] = w1[idx];
        }
        if (tid < 128) { Ws[tid*XSTR+150]=0.f; Ws[tid*XSTR+151]=0.f; }
        __syncthreads();

        // ---- GEMM1: H1 = relu(X @ W1^T + b1)  (8 samples x 4 outs per thread)
        {
            int so = tid & 7, jq = tid >> 3;
            float acc[8][4];
            #pragma unroll
            for (int m2=0;m2<8;m2++){ acc[m2][0]=0;acc[m2][1]=0;acc[m2][2]=0;acc[m2][3]=0; }
            for (int kk=0; kk<152; kk+=4) {
                float4 xv[8], wv[4];
                #pragma unroll
                for (int m2=0;m2<8;m2++) xv[m2] = *(const float4*)&Xs[(so*8+m2)*XSTR + kk];
                #pragma unroll
                for (int n=0;n<4;n++)   wv[n]  = *(const float4*)&Ws[(jq*4+n)*XSTR + kk];
                #pragma unroll
                for (int m2=0;m2<8;m2++)
                    #pragma unroll
                    for (int n=0;n<4;n++)
                        acc[m2][n] += xv[m2].x*wv[n].x + xv[m2].y*wv[n].y
                                    + xv[m2].z*wv[n].z + xv[m2].w*wv[n].w;
            }
            #pragma unroll
            for (int n=0;n<4;n++) {
                int j = jq*4+n; float bb = b1[j];
                #pragma unroll
                for (int m2=0;m2<8;m2++)
                    Hs[(so*8+m2)*HSTR + j] = fmaxf(acc[m2][n] + bb, 0.f);
            }
            if (tid < 64) *(float4*)&Hs[tid*HSTR+128] = make_float4(0,0,0,0);
        }
        __syncthreads();

        // ---- P4: stage W2 (stride HSTR)
        for (int idx = tid; idx < 16384; idx += 256) {
            int j = idx >> 7, k = idx & 127;
            Ws[j*HSTR + k] = w2[idx];
        }
        if (tid < 128) *(float4*)&Ws[tid*HSTR+128] = make_float4(0,0,0,0);
        __syncthreads();

        // ---- GEMM2: H2 = relu(H1 @ W2^T + b2) -> Xs region (stride HSTR)
        {
            int so = tid & 7, jq = tid >> 3;
            float acc[8][4];
            #pragma unroll
            for (int m2=0;m2<8;m2++){ acc[m2][0]=0;acc[m2][1]=0;acc[m2][2]=0;acc[m2][3]=0; }
            for (int kk=0; kk<132; kk+=4) {
                float4 xv[8], wv[4];
                #pragma unroll
                for (int m2=0;m2<8;m2++) xv[m2] = *(const float4*)&Hs[(so*8+m2)*HSTR + kk];
                #pragma unroll
                for (int n=0;n<4;n++)   wv[n]  = *(const float4*)&Ws[(jq*4+n)*HSTR + kk];
                #pragma unroll
                for (int m2=0;m2<8;m2++)
                    #pragma unroll
                    for (int n=0;n<4;n++)
                        acc[m2][n] += xv[m2].x*wv[n].x + xv[m2].y*wv[n].y
                                    + xv[m2].z*wv[n].z + xv[m2].w*wv[n].w;
            }
            #pragma unroll
            for (int n=0;n<4;n++) {
                int j = jq*4+n; float bb = b2[j];
                #pragma unroll
                for (int m2=0;m2<8;m2++)
                    Xs[(so*8+m2)*HSTR + j] = fmaxf(acc[m2][n] + bb, 0.f);
            }
        }
        __syncthreads();

        // ---- P5: rgb = sigmoid(H2 @ W3^T + b3); weighted accumulate per ray
        if (tid < 192) {
            int u = tid / 3, ch = tid - u*3;
            const float* h2 = Xs + u*HSTR;
            const float* wr = w3 + ch*128;
            float acc5 = b3[ch];
            for (int k=0;k<128;k+=4) {
                float4 hv  = *(const float4*)&h2[k];
                float4 wv4 = *(const float4*)&wr[k];
                acc5 += hv.x*wv4.x + hv.y*wv4.y + hv.z*wv4.z + hv.w*wv4.w;
            }
            float rgbv = 1.f/(1.f+expf(-acc5));
            float wgt  = g_w[u];
            if (wgt > 0.f) atomicAdd(&rgbacc[g_ray[u]*3+ch], wgt*rgbv);
        }
        __syncthreads();   // protect g_*/Ws before next tile
    }
}

// ---------------------------------------------------------------- finalize rgb_map
__global__ __launch_bounds__(256) void k_final(
    const float* __restrict__ rgbacc, const float* __restrict__ acc_out, float* __restrict__ out)
{
    int i = blockIdx.x*256 + threadIdx.x;
    if (i < NRAYS*3) {
        int r = i/3;
        out[i] = clampf(rgbacc[i] + (1.f - acc_out[r]), 0.f, 1.f);
    }
}

// ---------------------------------------------------------------- launch
extern "C" void kernel_launch(void* const* d_in, const int* in_sizes, int n_in,
                              void* d_out, int out_size, void* d_ws, size_t ws_size,
                              hipStream_t stream)
{
    const float* ro = (const float*)d_in[0];
    const float* rd = (const float*)d_in[1];
    const float* dplane[3] = {(const float*)d_in[2],(const float*)d_in[6],(const float*)d_in[10]};
    const float* dline[3]  = {(const float*)d_in[3],(const float*)d_in[7],(const float*)d_in[11]};
    const float* aplane[3] = {(const float*)d_in[4],(const float*)d_in[8],(const float*)d_in[12]};
    const float* aline[3]  = {(const float*)d_in[5],(const float*)d_in[9],(const float*)d_in[13]};
    const float* basis_w = (const float*)d_in[14];
    const float* w1 = (const float*)d_in[15];
    const float* b1 = (const float*)d_in[16];
    const float* w2 = (const float*)d_in[17];
    const float* b2 = (const float*)d_in[18];
    const float* w3 = (const float*)d_in[19];
    const float* b3 = (const float*)d_in[20];
    float* out = (float*)d_out;

    char* ws = (char*)d_ws;
    int*   counter = (int*)  (ws + 0);
    float* rgbacc  = (float*)(ws + 256);        // 3072 f
    float* accb    = (float*)(ws + 12544);      // 1024 f
    float* weights = (float*)(ws + 16640);      // 524288 f
    int*   list    = (int*)  (ws + 2113792);    // 524288 i
    float* planesT = (float*)(ws + 4210944);    // 6 * 1,440,000 f
    float* linesT  = (float*)(ws + 4210944 + (size_t)6*PLANE_ELEMS*4); // 6*4800 f

    hipMemsetAsync(ws, 0, 12544, stream);       // counter + rgbacc

    TPtrs tp;
    for (int i=0;i<3;i++) {
        tp.psrc[i]   = dplane[i]; tp.pdst[i]   = planesT + (size_t)i*PLANE_ELEMS;
        tp.psrc[3+i] = aplane[i]; tp.pdst[3+i] = planesT + (size_t)(3+i)*PLANE_ELEMS;
        tp.lsrc[i]   = dline[i];  tp.ldst[i]   = linesT + i*(GRIDN*16);
        tp.lsrc[3+i] = aline[i];  tp.ldst[3+i] = linesT + (3+i)*(GRIDN*16);
    }
    dim3 tg((POS_ELEMS+255)/256, 6);
    hipLaunchKernelGGL(k_transpose, tg, dim3(256), 0, stream, tp);

    k_density<<<NRAYS, NSAMP, 0, stream>>>(
        ro, rd,
        planesT + 0*(size_t)PLANE_ELEMS, planesT + 1*(size_t)PLANE_ELEMS, planesT + 2*(size_t)PLANE_ELEMS,
        linesT + 0*(GRIDN*16), linesT + 1*(GRIDN*16), linesT + 2*(GRIDN*16),
        weights, accb, out + NRAYS*3, list, counter);

    k_mlp<<<512, 256, 0, stream>>>(
        ro, rd,
        planesT + 3*(size_t)PLANE_ELEMS, planesT + 4*(size_t)PLANE_ELEMS, planesT + 5*(size_t)PLANE_ELEMS,
        linesT + 3*(GRIDN*16), linesT + 4*(GRIDN*16), linesT + 5*(GRIDN*16),
        basis_w, w1, b1, w2, b2, w3, b3,
        weights, list, counter, rgbacc);

    k_final<<<(NRAYS*3+255)/256, 256, 0, stream>>>(rgbacc, accb, out);
}

// Round 2
// 273.278 us; speedup vs baseline: 1.4691x; 1.4691x over previous
//
#include <hip/hip_runtime.h>
#include <math.h>

#define NRAYS 1024
#define NSAMP 512
#define GRIDN 300
#define POS_ELEMS (GRIDN*GRIDN)
#define PLANE_ELEMS (16*POS_ELEMS)

typedef short bf16x8 __attribute__((ext_vector_type(8)));
typedef float f32x4  __attribute__((ext_vector_type(4)));

__device__ __forceinline__ float clampf(float x, float a, float b){ return fminf(fmaxf(x,a),b); }
__device__ __forceinline__ unsigned short f2b(float f){
    unsigned u = __builtin_bit_cast(unsigned, f);
    u = (u + 0x7FFFu + ((u>>16)&1u)) >> 16;
    return (unsigned short)u;
}
__device__ __forceinline__ float b2f(unsigned short h){
    unsigned u = ((unsigned)h) << 16;
    return __builtin_bit_cast(float, u);
}

// ---------------------------------------------------------------- transpose
struct TPtrs {
    const float* psrc[6]; float* pdst[6];
    const float* lsrc[6]; float* ldst[6];
};

__global__ __launch_bounds__(256) void k_transpose(TPtrs tp) {
    int by  = blockIdx.y;
    int pos = blockIdx.x * 256 + threadIdx.x;
    if (pos < POS_ELEMS) {
        const float* src = tp.psrc[by];
        float v[16];
        #pragma unroll
        for (int c = 0; c < 16; c++) v[c] = src[c * POS_ELEMS + pos];
        float4* dst = (float4*)(tp.pdst[by] + (size_t)pos * 16);
        dst[0] = make_float4(v[0],v[1],v[2],v[3]);
        dst[1] = make_float4(v[4],v[5],v[6],v[7]);
        dst[2] = make_float4(v[8],v[9],v[10],v[11]);
        dst[3] = make_float4(v[12],v[13],v[14],v[15]);
    }
    if (pos < GRIDN) {
        const float* ls = tp.lsrc[by];
        float*       ld = tp.ldst[by];
        #pragma unroll
        for (int c = 0; c < 16; c++) ld[pos * 16 + c] = ls[c * GRIDN + pos];
    }
}

// ---------------------------------------------------------------- density + weights
__global__ __launch_bounds__(512) void k_density(
    const float* __restrict__ ro, const float* __restrict__ rd,
    const float* __restrict__ dpT0, const float* __restrict__ dpT1, const float* __restrict__ dpT2,
    const float* __restrict__ dlT0, const float* __restrict__ dlT1, const float* __restrict__ dlT2,
    float* __restrict__ weights, float* __restrict__ acc_out, float* __restrict__ depth_out,
    int* __restrict__ list, int* __restrict__ counter)
{
    const float STEPF = (3.0f/299.0f)*0.5f;
    int r = blockIdx.x;
    int s = threadIdx.x;
    int lane = s & 63, wv = s >> 6;

    float o0=ro[r*3+0], o1=ro[r*3+1], o2=ro[r*3+2];
    float d0=rd[r*3+0], d1=rd[r*3+1], d2=rd[r*3+2];

    float t_min = -1e30f;
    {
        float v0=(d0==0.f)?1e-6f:d0, v1=(d1==0.f)?1e-6f:d1, v2=(d2==0.f)?1e-6f:d2;
        float a,b;
        a=(1.5f-o0)/v0; b=(-1.5f-o0)/v0; t_min=fmaxf(t_min,fminf(a,b));
        a=(1.5f-o1)/v1; b=(-1.5f-o1)/v1; t_min=fmaxf(t_min,fminf(a,b));
        a=(1.5f-o2)/v2; b=(-1.5f-o2)/v2; t_min=fmaxf(t_min,fminf(a,b));
        t_min = clampf(t_min, 2.0f, 6.0f);
    }
    float z  = t_min + STEPF * (float)s;
    float p0 = o0 + d0*z, p1 = o1 + d1*z, p2 = o2 + d2*z;
    bool valid = (p0>=-1.5f)&&(p0<=1.5f)&&(p1>=-1.5f)&&(p1<=1.5f)&&(p2>=-1.5f)&&(p2<=1.5f);

    float sig = 0.f;
    if (valid) {
        float xn[3] = { (p0+1.5f)*(2.0f/3.0f)-1.0f,
                        (p1+1.5f)*(2.0f/3.0f)-1.0f,
                        (p2+1.5f)*(2.0f/3.0f)-1.0f };
        const float* dpT[3] = {dpT0,dpT1,dpT2};
        const float* dlT[3] = {dlT0,dlT1,dlT2};
        const int M0[3]={0,0,1}, M1[3]={1,2,2}, V[3]={2,1,0};
        float sf = 0.f;
        #pragma unroll
        for (int i=0;i<3;i++) {
            float fx = clampf((xn[M0[i]]*0.5f+0.5f)*299.f, 0.f, 299.f);
            float fy = clampf((xn[M1[i]]*0.5f+0.5f)*299.f, 0.f, 299.f);
            float ft = clampf((xn[V[i]] *0.5f+0.5f)*299.f, 0.f, 299.f);
            int x0=min((int)fx,298), y0=min((int)fy,298), i0=min((int)ft,298);
            float wx=fx-(float)x0, wy=fy-(float)y0, wt=ft-(float)i0;
            const float4* row0 = (const float4*)(dpT[i] + (size_t)(y0*GRIDN+x0)*16);
            const float4* row1 = (const float4*)(dpT[i] + (size_t)((y0+1)*GRIDN+x0)*16);
            const float4* ln   = (const float4*)(dlT[i] + (size_t)i0*16);
            #pragma unroll
            for (int q=0;q<4;q++) {
                float4 a00=row0[q], a01=row0[q+4], a10=row1[q], a11=row1[q+4];
                float4 l0=ln[q],   l1=ln[q+4];
                float bx = (a00.x*(1.f-wx)+a01.x*wx)*(1.f-wy) + (a10.x*(1.f-wx)+a11.x*wx)*wy;
                float by = (a00.y*(1.f-wx)+a01.y*wx)*(1.f-wy) + (a10.y*(1.f-wx)+a11.y*wx)*wy;
                float bz = (a00.z*(1.f-wx)+a01.z*wx)*(1.f-wy) + (a10.z*(1.f-wx)+a11.z*wx)*wy;
                float bw = (a00.w*(1.f-wx)+a01.w*wx)*(1.f-wy) + (a10.w*(1.f-wx)+a11.w*wx)*wy;
                float lx = l0.x*(1.f-wt)+l1.x*wt;
                float ly = l0.y*(1.f-wt)+l1.y*wt;
                float lz = l0.z*(1.f-wt)+l1.z*wt;
                float lw = l0.w*(1.f-wt)+l1.w*wt;
                sf += bx*lx + by*ly + bz*lz + bw*lw;
            }
        }
        float xs = sf - 10.0f;
        sig = fmaxf(xs, 0.f) + __logf(1.f + __expf(-fabsf(xs)));   // softplus
    }
    float alpha = (s < NSAMP-1) ? (1.f - __expf(-sig * (STEPF*25.0f))) : 0.f;

    // wave-level multiplicative inclusive scan of (1-alpha+eps)
    float v = (1.f - alpha) + 1e-10f;
    float inc = v;
    #pragma unroll
    for (int off=1; off<64; off<<=1) {
        float t = __shfl_up(inc, off, 64);
        if (lane >= off) inc *= t;
    }
    __shared__ float wtot[8], swsum[8], sdep[8];
    if (lane == 63) wtot[wv] = inc;
    __syncthreads();
    float pre = 1.f;
    for (int i=0;i<wv;i++) pre *= wtot[i];
    float excl = __shfl_up(inc, 1, 64);
    if (lane == 0) excl = 1.f;
    float T = pre * excl;
    float w = alpha * T;
    weights[r*NSAMP + s] = w;

    // fused reductions: sum(w), sum(w*z)
    float rw = w, rz = w*z;
    #pragma unroll
    for (int off=32; off>0; off>>=1) { rw += __shfl_xor(rw,off,64); rz += __shfl_xor(rz,off,64); }
    if (lane == 0) { swsum[wv] = rw; sdep[wv] = rz; }
    __syncthreads();
    if (s == 0) {
        float a=0.f, b=0.f;
        #pragma unroll
        for (int i=0;i<8;i++){ a+=swsum[i]; b+=sdep[i]; }
        acc_out[r] = a; depth_out[r] = b;
    }

    // wave-aggregated compaction of samples with weight > W_THRES
    bool act = (w > 1e-4f);
    unsigned long long m = __ballot(act);
    int cnt  = __popcll(m);
    if (cnt) {
        int base = 0;
        if (lane==0) base = atomicAdd(counter, cnt);
        base = __shfl(base, 0);
        if (act) {
            int pofs = __popcll(m & ((1ull<<lane)-1ull));
            list[base + pofs] = (r<<9) | s;
        }
    }
}

// ---------------------------------------------------------------- masked appearance + MFMA MLP
#define XST 168   // bf16 row stride for X/W1 (21*16B -> bank-spread)
#define HST 136   // bf16 row stride for H1/W2/H2 (17*16B)
#define CST 52    // f32 row stride for coefs

__global__ __launch_bounds__(512) void k_mlp(
    const float* __restrict__ ro, const float* __restrict__ rd,
    const float* __restrict__ apT0, const float* __restrict__ apT1, const float* __restrict__ apT2,
    const float* __restrict__ alT0, const float* __restrict__ alT1, const float* __restrict__ alT2,
    const float* __restrict__ basis_w, const float* __restrict__ w1p, const float* __restrict__ b1p,
    const float* __restrict__ w2p, const float* __restrict__ b2p,
    const float* __restrict__ w3p, const float* __restrict__ b3p,
    const float* __restrict__ weights, const int* __restrict__ list, const int* __restrict__ counter,
    float* __restrict__ rgbacc)
{
    __shared__ __align__(16) unsigned short Xs [64*XST];   // X (bf16), later H2 (stride HST)
    __shared__ __align__(16) unsigned short Ws1[128*XST];  // W1 resident
    __shared__ __align__(16) unsigned short Hs [64*HST];   // H1
    __shared__ __align__(16) unsigned short Ws2[128*HST];  // W2 resident
    __shared__ __align__(16) float Cs[64*CST];             // 48 appearance coefs per sample

    const float STEPF = (3.0f/299.0f)*0.5f;
    int tid  = threadIdx.x;
    int wvid = tid >> 6, lane = tid & 63, ln15 = lane & 15, kq = lane >> 4;

    // ---- one-time: stage W1/W2 as bf16 (k-padded with zeros)
    for (int idx = tid; idx < 128*XST; idx += 512) {
        int j = idx / XST, k = idx - j*XST;
        float v = (k < 150) ? w1p[j*150 + k] : 0.f;
        Ws1[idx] = f2b(v);
    }
    for (int idx = tid; idx < 128*HST; idx += 512) {
        int j = idx / HST, k = idx - j*HST;
        float v = (k < 128) ? w2p[j*128 + k] : 0.f;
        Ws2[idx] = f2b(v);
    }
    int count  = *counter;
    int ntiles = (count + 63) >> 6;
    __syncthreads();

    for (int t = blockIdx.x; t < ntiles; t += gridDim.x) {
        // ---- P1: appearance gather -> Cs (8 threads/sample, 6 active)
        {
            int u = tid >> 3, q = tid & 7;
            int idx = (t<<6) + u;
            if (q < 6) {
                int i = q >> 1, h = q & 1;
                if (idx < count) {
                    int sid = list[idx];
                    int r = sid >> 9, s = sid & (NSAMP-1);
                    float o0=ro[r*3+0], o1=ro[r*3+1], o2=ro[r*3+2];
                    float d0=rd[r*3+0], d1=rd[r*3+1], d2=rd[r*3+2];
                    float t_min = -1e30f;
                    float v0=(d0==0.f)?1e-6f:d0, v1=(d1==0.f)?1e-6f:d1, v2=(d2==0.f)?1e-6f:d2;
                    float a,b;
                    a=(1.5f-o0)/v0; b=(-1.5f-o0)/v0; t_min=fmaxf(t_min,fminf(a,b));
                    a=(1.5f-o1)/v1; b=(-1.5f-o1)/v1; t_min=fmaxf(t_min,fminf(a,b));
                    a=(1.5f-o2)/v2; b=(-1.5f-o2)/v2; t_min=fmaxf(t_min,fminf(a,b));
                    t_min = clampf(t_min, 2.0f, 6.0f);
                    float z = t_min + STEPF*(float)s;
                    float xn[3] = { ((o0+d0*z)+1.5f)*(2.0f/3.0f)-1.0f,
                                    ((o1+d1*z)+1.5f)*(2.0f/3.0f)-1.0f,
                                    ((o2+d2*z)+1.5f)*(2.0f/3.0f)-1.0f };
                    const float* apT[3]={apT0,apT1,apT2};
                    const float* alT[3]={alT0,alT1,alT2};
                    const int M0[3]={0,0,1}, M1[3]={1,2,2}, V[3]={2,1,0};
                    float fx = clampf((xn[M0[i]]*0.5f+0.5f)*299.f, 0.f, 299.f);
                    float fy = clampf((xn[M1[i]]*0.5f+0.5f)*299.f, 0.f, 299.f);
                    float ft = clampf((xn[V[i]] *0.5f+0.5f)*299.f, 0.f, 299.f);
                    int x0=min((int)fx,298), y0=min((int)fy,298), i0=min((int)ft,298);
                    float wx=fx-(float)x0, wy=fy-(float)y0, wt=ft-(float)i0;
                    const float4* row0 = (const float4*)(apT[i] + (size_t)(y0*GRIDN+x0)*16) + h*2;
                    const float4* row1 = (const float4*)(apT[i] + (size_t)((y0+1)*GRIDN+x0)*16) + h*2;
                    const float4* lnp  = (const float4*)(alT[i] + (size_t)i0*16) + h*2;
                    #pragma unroll
                    for (int q2=0; q2<2; q2++) {
                        float4 a00=row0[q2], a01=row0[q2+4], a10=row1[q2], a11=row1[q2+4];
                        float4 l0=lnp[q2],  l1=lnp[q2+4];
                        float cx=((a00.x*(1.f-wx)+a01.x*wx)*(1.f-wy)+(a10.x*(1.f-wx)+a11.x*wx)*wy)*(l0.x*(1.f-wt)+l1.x*wt);
                        float cy=((a00.y*(1.f-wx)+a01.y*wx)*(1.f-wy)+(a10.y*(1.f-wx)+a11.y*wx)*wy)*(l0.y*(1.f-wt)+l1.y*wt);
                        float cz=((a00.z*(1.f-wx)+a01.z*wx)*(1.f-wy)+(a10.z*(1.f-wx)+a11.z*wx)*wy)*(l0.z*(1.f-wt)+l1.z*wt);
                        float cw=((a00.w*(1.f-wx)+a01.w*wx)*(1.f-wy)+(a10.w*(1.f-wx)+a11.w*wx)*wy)*(l0.w*(1.f-wt)+l1.w*wt);
                        *(float4*)&Cs[u*CST + i*16 + h*8 + q2*4] = make_float4(cx,cy,cz,cw);
                    }
                } else {
                    *(float4*)&Cs[u*CST + i*16 + h*8 + 0] = make_float4(0,0,0,0);
                    *(float4*)&Cs[u*CST + i*16 + h*8 + 4] = make_float4(0,0,0,0);
                }
            }
        }
        __syncthreads();

        // ---- P2: feat = basis @ coefs, posenc -> Xs (bf16)
        {
            int u = tid >> 3, q = tid & 7;
            unsigned short* X = Xs + u*XST;
            const float* C = Cs + u*CST;
            for (int j=q; j<27; j+=8) {
                float f = 0.f;
                const float* bwp = basis_w + j*48;
                #pragma unroll
                for (int k=0;k<48;k++) f += bwp[k]*C[k];
                X[j]      = f2b(f);
                X[30+2*j] = f2b(__sinf(f));     X[31+2*j] = f2b(__sinf(2.f*f));
                X[84+2*j] = f2b(__cosf(f));     X[85+2*j] = f2b(__cosf(2.f*f));
            }
            if (q == 7) {
                int idx = (t<<6) + u;
                float vd[3] = {0.f,0.f,0.f};
                if (idx < count) {
                    int r = list[idx] >> 9;
                    vd[0]=rd[r*3+0]; vd[1]=rd[r*3+1]; vd[2]=rd[r*3+2];
                }
                #pragma unroll
                for (int c=0;c<3;c++) {
                    float vv = vd[c];
                    X[27+c]     = f2b(vv);
                    X[138+2*c]  = f2b(__sinf(vv));  X[139+2*c] = f2b(__sinf(2.f*vv));
                    X[144+2*c]  = f2b(__cosf(vv));  X[145+2*c] = f2b(__cosf(2.f*vv));
                }
                #pragma unroll
                for (int k=150;k<XST;k++) X[k] = 0;   // k-pad
            }
        }
        __syncthreads();

        // ---- GEMM1 (MFMA): H1 = relu(X @ W1^T + b1), 64x128, K=160
        {
            int mt0 = (wvid & 1) * 2;       // 2 M-tiles of 16
            int nt0 = (wvid >> 1) * 2;      // 2 N-tiles of 16
            f32x4 acc[2][2] = {};
            #pragma unroll
            for (int ks=0; ks<5; ks++) {
                int ko = ks*32 + kq*8;
                bf16x8 a0 = *(const bf16x8*)&Xs [((mt0  )*16 + ln15)*XST + ko];
                bf16x8 a1 = *(const bf16x8*)&Xs [((mt0+1)*16 + ln15)*XST + ko];
                bf16x8 b0 = *(const bf16x8*)&Ws1[((nt0  )*16 + ln15)*XST + ko];
                bf16x8 b1 = *(const bf16x8*)&Ws1[((nt0+1)*16 + ln15)*XST + ko];
                acc[0][0] = __builtin_amdgcn_mfma_f32_16x16x32_bf16(a0,b0,acc[0][0],0,0,0);
                acc[0][1] = __builtin_amdgcn_mfma_f32_16x16x32_bf16(a0,b1,acc[0][1],0,0,0);
                acc[1][0] = __builtin_amdgcn_mfma_f32_16x16x32_bf16(a1,b0,acc[1][0],0,0,0);
                acc[1][1] = __builtin_amdgcn_mfma_f32_16x16x32_bf16(a1,b1,acc[1][1],0,0,0);
            }
            #pragma unroll
            for (int jn=0;jn<2;jn++) {
                int col = (nt0+jn)*16 + ln15;
                float bias = b1p[col];
                #pragma unroll
                for (int i=0;i<2;i++) {
                    int rbase = (mt0+i)*16 + kq*4;
                    #pragma unroll
                    for (int j=0;j<4;j++)
                        Hs[(rbase+j)*HST + col] = f2b(fmaxf(acc[i][jn][j] + bias, 0.f));
                }
            }
        }
        __syncthreads();

        // ---- GEMM2 (MFMA): H2 = relu(H1 @ W2^T + b2) -> Xs region (stride HST)
        {
            int mt0 = (wvid & 1) * 2;
            int nt0 = (wvid >> 1) * 2;
            f32x4 acc[2][2] = {};
            #pragma unroll
            for (int ks=0; ks<4; ks++) {
                int ko = ks*32 + kq*8;
                bf16x8 a0 = *(const bf16x8*)&Hs [((mt0  )*16 + ln15)*HST + ko];
                bf16x8 a1 = *(const bf16x8*)&Hs [((mt0+1)*16 + ln15)*HST + ko];
                bf16x8 b0 = *(const bf16x8*)&Ws2[((nt0  )*16 + ln15)*HST + ko];
                bf16x8 b1 = *(const bf16x8*)&Ws2[((nt0+1)*16 + ln15)*HST + ko];
                acc[0][0] = __builtin_amdgcn_mfma_f32_16x16x32_bf16(a0,b0,acc[0][0],0,0,0);
                acc[0][1] = __builtin_amdgcn_mfma_f32_16x16x32_bf16(a0,b1,acc[0][1],0,0,0);
                acc[1][0] = __builtin_amdgcn_mfma_f32_16x16x32_bf16(a1,b0,acc[1][0],0,0,0);
                acc[1][1] = __builtin_amdgcn_mfma_f32_16x16x32_bf16(a1,b1,acc[1][1],0,0,0);
            }
            #pragma unroll
            for (int jn=0;jn<2;jn++) {
                int col = (nt0+jn)*16 + ln15;
                float bias = b2p[col];
                #pragma unroll
                for (int i=0;i<2;i++) {
                    int rbase = (mt0+i)*16 + kq*4;
                    #pragma unroll
                    for (int j=0;j<4;j++)
                        Xs[(rbase+j)*HST + col] = f2b(fmaxf(acc[i][jn][j] + bias, 0.f));
                }
            }
        }
        __syncthreads();

        // ---- P5: rgb = sigmoid(H2 @ W3^T + b3); weighted accumulate
        if (tid < 256) {
            int u = tid >> 2, ch = tid & 3;
            if (ch < 3) {
                int idx = (t<<6) + u;
                if (idx < count) {
                    int sid = list[idx];
                    float wgt = weights[sid];
                    if (wgt > 0.f) {
                        const unsigned short* h2 = Xs + u*HST;
                        const float* wr = w3p + ch*128;
                        float acc5 = b3p[ch];
                        #pragma unroll
                        for (int k=0;k<128;k+=8) {
                            bf16x8 hv = *(const bf16x8*)&h2[k];
                            #pragma unroll
                            for (int e=0;e<8;e++)
                                acc5 += b2f((unsigned short)hv[e]) * wr[k+e];
                        }
                        float rgbv = 1.f/(1.f + __expf(-acc5));
                        atomicAdd(&rgbacc[(sid>>9)*3 + ch], wgt*rgbv);
                    }
                }
            }
        }
        __syncthreads();   // protect Cs/Xs/Hs before next tile
    }
}

// ---------------------------------------------------------------- finalize rgb_map
__global__ __launch_bounds__(256) void k_final(
    const float* __restrict__ rgbacc, const float* __restrict__ acc_out, float* __restrict__ out)
{
    int i = blockIdx.x*256 + threadIdx.x;
    if (i < NRAYS*3) {
        int r = i/3;
        out[i] = clampf(rgbacc[i] + (1.f - acc_out[r]), 0.f, 1.f);
    }
}

// ---------------------------------------------------------------- launch
extern "C" void kernel_launch(void* const* d_in, const int* in_sizes, int n_in,
                              void* d_out, int out_size, void* d_ws, size_t ws_size,
                              hipStream_t stream)
{
    const float* ro = (const float*)d_in[0];
    const float* rd = (const float*)d_in[1];
    const float* dplane[3] = {(const float*)d_in[2],(const float*)d_in[6],(const float*)d_in[10]};
    const float* dline[3]  = {(const float*)d_in[3],(const float*)d_in[7],(const float*)d_in[11]};
    const float* aplane[3] = {(const float*)d_in[4],(const float*)d_in[8],(const float*)d_in[12]};
    const float* aline[3]  = {(const float*)d_in[5],(const float*)d_in[9],(const float*)d_in[13]};
    const float* basis_w = (const float*)d_in[14];
    const float* w1 = (const float*)d_in[15];
    const float* b1 = (const float*)d_in[16];
    const float* w2 = (const float*)d_in[17];
    const float* b2 = (const float*)d_in[18];
    const float* w3 = (const float*)d_in[19];
    const float* b3 = (const float*)d_in[20];
    float* out = (float*)d_out;

    char* ws = (char*)d_ws;
    int*   counter = (int*)  (ws + 0);
    float* rgbacc  = (float*)(ws + 256);        // 3072 f
    float* accb    = (float*)(ws + 12544);      // 1024 f
    float* weights = (float*)(ws + 16640);      // 524288 f
    int*   list    = (int*)  (ws + 2113792);    // 524288 i
    float* planesT = (float*)(ws + 4210944);    // 6 * 1,440,000 f
    float* linesT  = (float*)(ws + 4210944 + (size_t)6*PLANE_ELEMS*4); // 6*4800 f

    hipMemsetAsync(ws, 0, 12544, stream);       // counter + rgbacc

    TPtrs tp;
    for (int i=0;i<3;i++) {
        tp.psrc[i]   = dplane[i]; tp.pdst[i]   = planesT + (size_t)i*PLANE_ELEMS;
        tp.psrc[3+i] = aplane[i]; tp.pdst[3+i] = planesT + (size_t)(3+i)*PLANE_ELEMS;
        tp.lsrc[i]   = dline[i];  tp.ldst[i]   = linesT + i*(GRIDN*16);
        tp.lsrc[3+i] = aline[i];  tp.ldst[3+i] = linesT + (3+i)*(GRIDN*16);
    }
    dim3 tg((POS_ELEMS+255)/256, 6);
    hipLaunchKernelGGL(k_transpose, tg, dim3(256), 0, stream, tp);

    k_density<<<NRAYS, NSAMP, 0, stream>>>(
        ro, rd,
        planesT + 0*(size_t)PLANE_ELEMS, planesT + 1*(size_t)PLANE_ELEMS, planesT + 2*(size_t)PLANE_ELEMS,
        linesT + 0*(GRIDN*16), linesT + 1*(GRIDN*16), linesT + 2*(GRIDN*16),
        weights, accb, out + NRAYS*3, list, counter);

    k_mlp<<<256, 512, 0, stream>>>(
        ro, rd,
        planesT + 3*(size_t)PLANE_ELEMS, planesT + 4*(size_t)PLANE_ELEMS, planesT + 5*(size_t)PLANE_ELEMS,
        linesT + 3*(GRIDN*16), linesT + 4*(GRIDN*16), linesT + 5*(GRIDN*16),
        basis_w, w1, b1, w2, b2, w3, b3,
        weights, list, counter, rgbacc);

    k_final<<<(NRAYS*3+255)/256, 256, 0, stream>>>(rgbacc, accb, out);
}

// Round 5
// 232.732 us; speedup vs baseline: 1.7251x; 1.1742x over previous
//
#include <hip/hip_runtime.h>
#include <hip/hip_fp16.h>
#include <math.h>

#define NRAYS 1024
#define NSAMP 512
#define GRIDN 300
#define POS_ELEMS (GRIDN*GRIDN)
#define PLANE_ELEMS (16*POS_ELEMS)

typedef short bf16x8 __attribute__((ext_vector_type(8)));
typedef float f32x4  __attribute__((ext_vector_type(4)));

struct H8v { __half2 h[4]; };    // 8 fp16 = 16B

__device__ __forceinline__ float clampf(float x, float a, float b){ return fminf(fmaxf(x,a),b); }
__device__ __forceinline__ unsigned short f2b(float f){
    unsigned u = __builtin_bit_cast(unsigned, f);
    u = (u + 0x7FFFu + ((u>>16)&1u)) >> 16;
    return (unsigned short)u;
}
__device__ __forceinline__ float b2f(unsigned short h){
    unsigned u = ((unsigned)h) << 16;
    return __builtin_bit_cast(float, u);
}

// ---------------------------------------------------------------- transpose
// density planes/lines -> channel-last f32; appearance -> channel-last fp16
struct TPtrs {
    const float* psrc[6];
    float*  pdstf[3];  __half* pdsth[3];
    const float* lsrc[6];
    float*  ldstf[3];  __half* ldsth[3];
};

__global__ __launch_bounds__(256) void k_transpose(TPtrs tp) {
    int by  = blockIdx.y;
    int pos = blockIdx.x * 256 + threadIdx.x;
    if (by < 3) {   // density: f32 out
        if (pos < POS_ELEMS) {
            const float* src = tp.psrc[by];
            float v[16];
            #pragma unroll
            for (int c = 0; c < 16; c++) v[c] = src[c * POS_ELEMS + pos];
            float4* dst = (float4*)(tp.pdstf[by] + (size_t)pos * 16);
            dst[0] = make_float4(v[0],v[1],v[2],v[3]);
            dst[1] = make_float4(v[4],v[5],v[6],v[7]);
            dst[2] = make_float4(v[8],v[9],v[10],v[11]);
            dst[3] = make_float4(v[12],v[13],v[14],v[15]);
        }
        if (pos < GRIDN) {
            const float* ls = tp.lsrc[by];
            float*       ld = tp.ldstf[by];
            #pragma unroll
            for (int c = 0; c < 16; c++) ld[pos * 16 + c] = ls[c * GRIDN + pos];
        }
    } else {        // appearance: fp16 out
        int ai = by - 3;
        if (pos < POS_ELEMS) {
            const float* src = tp.psrc[by];
            __half2 o[8];
            #pragma unroll
            for (int e = 0; e < 8; e++) {
                float a = src[(2*e  ) * POS_ELEMS + pos];
                float b = src[(2*e+1) * POS_ELEMS + pos];
                o[e] = __float22half2_rn(make_float2(a,b));
            }
            float4* dst = (float4*)(tp.pdsth[ai] + (size_t)pos * 16);
            dst[0] = *(float4*)&o[0];
            dst[1] = *(float4*)&o[4];
        }
        if (pos < GRIDN) {
            const float* ls = tp.lsrc[by];
            __half*      ld = tp.ldsth[ai];
            #pragma unroll
            for (int c = 0; c < 16; c++) ld[pos * 16 + c] = __float2half_rn(ls[c * GRIDN + pos]);
        }
    }
}

// ---------------------------------------------------------------- density + weights (f32)
__global__ __launch_bounds__(512) void k_density(
    const float* __restrict__ ro, const float* __restrict__ rd,
    const float* __restrict__ dpT0, const float* __restrict__ dpT1, const float* __restrict__ dpT2,
    const float* __restrict__ dlT0, const float* __restrict__ dlT1, const float* __restrict__ dlT2,
    float* __restrict__ weights, float* __restrict__ acc_out, float* __restrict__ depth_out,
    int* __restrict__ list, int* __restrict__ counter)
{
    const float STEPF = (3.0f/299.0f)*0.5f;
    int r = blockIdx.x;
    int s = threadIdx.x;
    int lane = s & 63, wv = s >> 6;

    float o0=ro[r*3+0], o1=ro[r*3+1], o2=ro[r*3+2];
    float d0=rd[r*3+0], d1=rd[r*3+1], d2=rd[r*3+2];

    float t_min = -1e30f;
    {
        float v0=(d0==0.f)?1e-6f:d0, v1=(d1==0.f)?1e-6f:d1, v2=(d2==0.f)?1e-6f:d2;
        float a,b;
        a=(1.5f-o0)/v0; b=(-1.5f-o0)/v0; t_min=fmaxf(t_min,fminf(a,b));
        a=(1.5f-o1)/v1; b=(-1.5f-o1)/v1; t_min=fmaxf(t_min,fminf(a,b));
        a=(1.5f-o2)/v2; b=(-1.5f-o2)/v2; t_min=fmaxf(t_min,fminf(a,b));
        t_min = clampf(t_min, 2.0f, 6.0f);
    }
    float z  = t_min + STEPF * (float)s;
    float p0 = o0 + d0*z, p1 = o1 + d1*z, p2 = o2 + d2*z;
    bool valid = (p0>=-1.5f)&&(p0<=1.5f)&&(p1>=-1.5f)&&(p1<=1.5f)&&(p2>=-1.5f)&&(p2<=1.5f);

    float sig = 0.f;
    if (valid) {
        float xn[3] = { (p0+1.5f)*(2.0f/3.0f)-1.0f,
                        (p1+1.5f)*(2.0f/3.0f)-1.0f,
                        (p2+1.5f)*(2.0f/3.0f)-1.0f };
        const float* dpT[3] = {dpT0,dpT1,dpT2};
        const float* dlT[3] = {dlT0,dlT1,dlT2};
        const int M0[3]={0,0,1}, M1[3]={1,2,2}, V[3]={2,1,0};
        float sf = 0.f;
        #pragma unroll
        for (int i=0;i<3;i++) {
            float fx = clampf((xn[M0[i]]*0.5f+0.5f)*299.f, 0.f, 299.f);
            float fy = clampf((xn[M1[i]]*0.5f+0.5f)*299.f, 0.f, 299.f);
            float ft = clampf((xn[V[i]] *0.5f+0.5f)*299.f, 0.f, 299.f);
            int x0=min((int)fx,298), y0=min((int)fy,298), i0=min((int)ft,298);
            float wx=fx-(float)x0, wy=fy-(float)y0, wt=ft-(float)i0;
            const float4* row0 = (const float4*)(dpT[i] + (size_t)(y0*GRIDN+x0)*16);
            const float4* row1 = (const float4*)(dpT[i] + (size_t)((y0+1)*GRIDN+x0)*16);
            const float4* ln   = (const float4*)(dlT[i] + (size_t)i0*16);
            #pragma unroll
            for (int q=0;q<4;q++) {
                float4 a00=row0[q], a01=row0[q+4], a10=row1[q], a11=row1[q+4];
                float4 l0=ln[q],   l1=ln[q+4];
                float bx = (a00.x*(1.f-wx)+a01.x*wx)*(1.f-wy) + (a10.x*(1.f-wx)+a11.x*wx)*wy;
                float by = (a00.y*(1.f-wx)+a01.y*wx)*(1.f-wy) + (a10.y*(1.f-wx)+a11.y*wx)*wy;
                float bz = (a00.z*(1.f-wx)+a01.z*wx)*(1.f-wy) + (a10.z*(1.f-wx)+a11.z*wx)*wy;
                float bw = (a00.w*(1.f-wx)+a01.w*wx)*(1.f-wy) + (a10.w*(1.f-wx)+a11.w*wx)*wy;
                float lx = l0.x*(1.f-wt)+l1.x*wt;
                float ly = l0.y*(1.f-wt)+l1.y*wt;
                float lz = l0.z*(1.f-wt)+l1.z*wt;
                float lw = l0.w*(1.f-wt)+l1.w*wt;
                sf += bx*lx + by*ly + bz*lz + bw*lw;
            }
        }
        float xs = sf - 10.0f;
        sig = fmaxf(xs, 0.f) + __logf(1.f + __expf(-fabsf(xs)));   // softplus
    }
    float alpha = (s < NSAMP-1) ? (1.f - __expf(-sig * (STEPF*25.0f))) : 0.f;

    // wave-level multiplicative inclusive scan of (1-alpha+eps)
    float v = (1.f - alpha) + 1e-10f;
    float inc = v;
    #pragma unroll
    for (int off=1; off<64; off<<=1) {
        float t = __shfl_up(inc, off, 64);
        if (lane >= off) inc *= t;
    }
    __shared__ float wtot[8], swsum[8], sdep[8];
    if (lane == 63) wtot[wv] = inc;
    __syncthreads();
    float pre = 1.f;
    for (int i=0;i<wv;i++) pre *= wtot[i];
    float excl = __shfl_up(inc, 1, 64);
    if (lane == 0) excl = 1.f;
    float T = pre * excl;
    float w = alpha * T;
    weights[r*NSAMP + s] = w;

    float rw = w, rz = w*z;
    #pragma unroll
    for (int off=32; off>0; off>>=1) { rw += __shfl_xor(rw,off,64); rz += __shfl_xor(rz,off,64); }
    if (lane == 0) { swsum[wv] = rw; sdep[wv] = rz; }
    __syncthreads();
    if (s == 0) {
        float a=0.f, b=0.f;
        #pragma unroll
        for (int i=0;i<8;i++){ a+=swsum[i]; b+=sdep[i]; }
        acc_out[r] = a; depth_out[r] = b;
    }

    bool act = (w > 1e-4f);
    unsigned long long m = __ballot(act);
    int cnt  = __popcll(m);
    if (cnt) {
        int base = 0;
        if (lane==0) base = atomicAdd(counter, cnt);
        base = __shfl(base, 0);
        if (act) {
            int pofs = __popcll(m & ((1ull<<lane)-1ull));
            list[base + pofs] = (r<<9) | s;
        }
    }
}

// ---------------------------------------------------------------- masked appearance + MFMA MLP
#define XST 168   // bf16 row stride for X (21*16B -> bank-spread)
#define HST 136   // bf16 row stride for H1/H2 (17*16B)
#define CST 52    // f32 row stride for coefs

__global__ __launch_bounds__(512, 4) void k_mlp(
    const float* __restrict__ ro, const float* __restrict__ rd,
    const __half* __restrict__ apT0, const __half* __restrict__ apT1, const __half* __restrict__ apT2,
    const __half* __restrict__ alT0, const __half* __restrict__ alT1, const __half* __restrict__ alT2,
    const float* __restrict__ basis_w, const float* __restrict__ w1p, const float* __restrict__ b1p,
    const float* __restrict__ w2p, const float* __restrict__ b2p,
    const float* __restrict__ w3p, const float* __restrict__ b3p,
    const float* __restrict__ weights, const int* __restrict__ list, const int* __restrict__ counter,
    float* __restrict__ rgbacc)
{
    __shared__ __align__(16) unsigned short Xs[64*XST];   // X (bf16), later H2 (stride HST)
    __shared__ __align__(16) unsigned short Hs[64*HST];   // H1
    __shared__ __align__(16) float Cs[64*CST];            // 48 appearance coefs per sample

    const float STEPF = (3.0f/299.0f)*0.5f;
    int tid  = threadIdx.x;
    int wvid = tid >> 6, lane = tid & 63, ln15 = lane & 15, kq = lane >> 4;

    // ---- weights -> VGPRs: wave wvid owns N-columns [16*wvid, 16*wvid+16)
    int jrow = (wvid<<4) + ln15;
    bf16x8 w1f[5], w2f[4];
    #pragma unroll
    for (int ks=0; ks<4; ks++) {
        int ko = ks*32 + kq*8;
        #pragma unroll
        for (int e=0;e<8;e++) w1f[ks][e] = (short)f2b(w1p[jrow*150 + ko + e]);
    }
    {
        int ko = 128 + kq*8;
        #pragma unroll
        for (int e=0;e<8;e++) {
            int k = ko + e;
            w1f[4][e] = (short)((k < 150) ? f2b(w1p[jrow*150 + k]) : 0);
        }
    }
    #pragma unroll
    for (int ks=0; ks<4; ks++) {
        int ko = ks*32 + kq*8;
        #pragma unroll
        for (int e=0;e<8;e++) w2f[ks][e] = (short)f2b(w2p[jrow*128 + ko + e]);
    }
    float bias1 = b1p[jrow];
    float bias2 = b2p[jrow];

    int count  = *counter;
    int ntiles = (count + 63) >> 6;

    for (int t = blockIdx.x; t < ntiles; t += gridDim.x) {
        // ---- P1: appearance gather (fp16) -> Cs
        {
            int u = tid >> 3, q = tid & 7;
            int idx = (t<<6) + u;
            if (q < 6) {
                int i = q >> 1, h = q & 1;
                if (idx < count) {
                    int sid = list[idx];
                    int r = sid >> 9, s = sid & (NSAMP-1);
                    float o0=ro[r*3+0], o1=ro[r*3+1], o2=ro[r*3+2];
                    float d0=rd[r*3+0], d1=rd[r*3+1], d2=rd[r*3+2];
                    float t_min = -1e30f;
                    float v0=(d0==0.f)?1e-6f:d0, v1=(d1==0.f)?1e-6f:d1, v2=(d2==0.f)?1e-6f:d2;
                    float a,b;
                    a=(1.5f-o0)/v0; b=(-1.5f-o0)/v0; t_min=fmaxf(t_min,fminf(a,b));
                    a=(1.5f-o1)/v1; b=(-1.5f-o1)/v1; t_min=fmaxf(t_min,fminf(a,b));
                    a=(1.5f-o2)/v2; b=(-1.5f-o2)/v2; t_min=fmaxf(t_min,fminf(a,b));
                    t_min = clampf(t_min, 2.0f, 6.0f);
                    float z = t_min + STEPF*(float)s;
                    float xn[3] = { ((o0+d0*z)+1.5f)*(2.0f/3.0f)-1.0f,
                                    ((o1+d1*z)+1.5f)*(2.0f/3.0f)-1.0f,
                                    ((o2+d2*z)+1.5f)*(2.0f/3.0f)-1.0f };
                    const __half* apT[3]={apT0,apT1,apT2};
                    const __half* alT[3]={alT0,alT1,alT2};
                    const int M0[3]={0,0,1}, M1[3]={1,2,2}, V[3]={2,1,0};
                    float fx = clampf((xn[M0[i]]*0.5f+0.5f)*299.f, 0.f, 299.f);
                    float fy = clampf((xn[M1[i]]*0.5f+0.5f)*299.f, 0.f, 299.f);
                    float ft = clampf((xn[V[i]] *0.5f+0.5f)*299.f, 0.f, 299.f);
                    int x0=min((int)fx,298), y0=min((int)fy,298), i0=min((int)ft,298);
                    float wx=fx-(float)x0, wy=fy-(float)y0, wt=ft-(float)i0;
                    __half2 w00=__float2half2_rn((1.f-wx)*(1.f-wy)), w01=__float2half2_rn(wx*(1.f-wy));
                    __half2 w10=__float2half2_rn((1.f-wx)*wy),       w11=__float2half2_rn(wx*wy);
                    __half2 u0 =__float2half2_rn(1.f-wt),            u1 =__float2half2_rn(wt);
                    const __half* base = apT[i] + (size_t)(y0*GRIDN+x0)*16 + h*8;
                    H8v a00 = *(const H8v*)(base);
                    H8v a01 = *(const H8v*)(base + 16);
                    H8v a10 = *(const H8v*)(base + GRIDN*16);
                    H8v a11 = *(const H8v*)(base + GRIDN*16 + 16);
                    const __half* lb = alT[i] + (size_t)i0*16 + h*8;
                    H8v l0 = *(const H8v*)(lb);
                    H8v l1 = *(const H8v*)(lb + 16);
                    float* C = &Cs[u*CST + i*16 + h*8];
                    #pragma unroll
                    for (int e=0;e<4;e++) {
                        __half2 p = __hmul2(a00.h[e],w00);
                        p = __hfma2(a01.h[e],w01,p);
                        p = __hfma2(a10.h[e],w10,p);
                        p = __hfma2(a11.h[e],w11,p);
                        __half2 l = __hmul2(l0.h[e],u0);
                        l = __hfma2(l1.h[e],u1,l);
                        float2 c = __half22float2(__hmul2(p,l));
                        C[2*e] = c.x; C[2*e+1] = c.y;
                    }
                } else {
                    float* C = &Cs[u*CST + i*16 + h*8];
                    #pragma unroll
                    for (int e=0;e<8;e++) C[e] = 0.f;
                }
            }
        }
        __syncthreads();

        // ---- P2: feat = basis @ coefs, posenc -> Xs (bf16)
        {
            int u = tid >> 3, q = tid & 7;
            unsigned short* X = Xs + u*XST;
            const float* C = Cs + u*CST;
            for (int j=q; j<27; j+=8) {
                float f = 0.f;
                const float* bwp = basis_w + j*48;
                #pragma unroll
                for (int k=0;k<48;k++) f += bwp[k]*C[k];
                X[j]      = f2b(f);
                X[30+2*j] = f2b(__sinf(f));     X[31+2*j] = f2b(__sinf(2.f*f));
                X[84+2*j] = f2b(__cosf(f));     X[85+2*j] = f2b(__cosf(2.f*f));
            }
            if (q == 7) {
                int idx = (t<<6) + u;
                float vd[3] = {0.f,0.f,0.f};
                if (idx < count) {
                    int r = list[idx] >> 9;
                    vd[0]=rd[r*3+0]; vd[1]=rd[r*3+1]; vd[2]=rd[r*3+2];
                }
                #pragma unroll
                for (int c=0;c<3;c++) {
                    float vv = vd[c];
                    X[27+c]     = f2b(vv);
                    X[138+2*c]  = f2b(__sinf(vv));  X[139+2*c] = f2b(__sinf(2.f*vv));
                    X[144+2*c]  = f2b(__cosf(vv));  X[145+2*c] = f2b(__cosf(2.f*vv));
                }
                #pragma unroll
                for (int k=150;k<XST;k++) X[k] = 0;   // k-pad
            }
        }
        __syncthreads();

        // ---- GEMM1 (MFMA): H1 = relu(X @ W1^T + b1); wave owns 16 cols, 4 M-tiles
        {
            f32x4 acc[4] = {};
            #pragma unroll
            for (int ks=0; ks<5; ks++) {
                int ko = ks*32 + kq*8;
                #pragma unroll
                for (int m=0;m<4;m++) {
                    bf16x8 a = *(const bf16x8*)&Xs[(m*16 + ln15)*XST + ko];
                    acc[m] = __builtin_amdgcn_mfma_f32_16x16x32_bf16(a, w1f[ks], acc[m], 0,0,0);
                }
            }
            int col = jrow;
            #pragma unroll
            for (int m=0;m<4;m++) {
                int rbase = m*16 + kq*4;
                #pragma unroll
                for (int j=0;j<4;j++)
                    Hs[(rbase+j)*HST + col] = f2b(fmaxf(acc[m][j] + bias1, 0.f));
            }
        }
        __syncthreads();

        // ---- GEMM2 (MFMA): H2 = relu(H1 @ W2^T + b2) -> Xs region (stride HST)
        {
            f32x4 acc[4] = {};
            #pragma unroll
            for (int ks=0; ks<4; ks++) {
                int ko = ks*32 + kq*8;
                #pragma unroll
                for (int m=0;m<4;m++) {
                    bf16x8 a = *(const bf16x8*)&Hs[(m*16 + ln15)*HST + ko];
                    acc[m] = __builtin_amdgcn_mfma_f32_16x16x32_bf16(a, w2f[ks], acc[m], 0,0,0);
                }
            }
            int col = jrow;
            #pragma unroll
            for (int m=0;m<4;m++) {
                int rbase = m*16 + kq*4;
                #pragma unroll
                for (int j=0;j<4;j++)
                    Xs[(rbase+j)*HST + col] = f2b(fmaxf(acc[m][j] + bias2, 0.f));
            }
        }
        __syncthreads();

        // ---- P5: rgb = sigmoid(H2 @ W3^T + b3); plain per-sample atomics
        if (tid < 256) {
            int u = tid >> 2, ch = tid & 3;
            int idx = (t<<6) + u;
            if (ch < 3 && idx < count) {
                int sid = list[idx];
                float wgt = weights[sid];
                if (wgt > 0.f) {
                    const unsigned short* h2 = Xs + u*HST;
                    const float* wr = w3p + ch*128;
                    float acc5 = b3p[ch];
                    #pragma unroll
                    for (int k=0;k<128;k+=8) {
                        bf16x8 hv = *(const bf16x8*)&h2[k];
                        #pragma unroll
                        for (int e=0;e<8;e++)
                            acc5 += b2f((unsigned short)hv[e]) * wr[k+e];
                    }
                    float rgbv = 1.f/(1.f + __expf(-acc5));
                    atomicAdd(&rgbacc[(sid>>9)*3 + ch], wgt*rgbv);
                }
            }
        }
        __syncthreads();   // protect Cs/Xs/Hs before next tile
    }
}

// ---------------------------------------------------------------- finalize rgb_map
__global__ __launch_bounds__(256) void k_final(
    const float* __restrict__ rgbacc, const float* __restrict__ acc_out, float* __restrict__ out)
{
    int i = blockIdx.x*256 + threadIdx.x;
    if (i < NRAYS*3) {
        int r = i/3;
        out[i] = clampf(rgbacc[i] + (1.f - acc_out[r]), 0.f, 1.f);
    }
}

// ---------------------------------------------------------------- launch
extern "C" void kernel_launch(void* const* d_in, const int* in_sizes, int n_in,
                              void* d_out, int out_size, void* d_ws, size_t ws_size,
                              hipStream_t stream)
{
    const float* ro = (const float*)d_in[0];
    const float* rd = (const float*)d_in[1];
    const float* dplane[3] = {(const float*)d_in[2],(const float*)d_in[6],(const float*)d_in[10]};
    const float* dline[3]  = {(const float*)d_in[3],(const float*)d_in[7],(const float*)d_in[11]};
    const float* aplane[3] = {(const float*)d_in[4],(const float*)d_in[8],(const float*)d_in[12]};
    const float* aline[3]  = {(const float*)d_in[5],(const float*)d_in[9],(const float*)d_in[13]};
    const float* basis_w = (const float*)d_in[14];
    const float* w1 = (const float*)d_in[15];
    const float* b1 = (const float*)d_in[16];
    const float* w2 = (const float*)d_in[17];
    const float* b2 = (const float*)d_in[18];
    const float* w3 = (const float*)d_in[19];
    const float* b3 = (const float*)d_in[20];
    float* out = (float*)d_out;

    char* ws = (char*)d_ws;
    int*    counter  = (int*)   (ws + 0);
    float*  rgbacc   = (float*) (ws + 256);        // 3072 f
    float*  accb     = (float*) (ws + 12544);      // 1024 f
    float*  weights  = (float*) (ws + 16640);      // 524288 f
    int*    list     = (int*)   (ws + 2113792);    // 524288 i
    float*  dplanesT = (float*) (ws + 4210944);    // 3 * 1,440,000 f  = 17,280,000 B
    float*  dlinesT  = (float*) (ws + 21490944);   // 3 * 4800 f      = 57,600 B
    __half* aplanesT = (__half*)(ws + 21548544);   // 3 * 1,440,000 h = 8,640,000 B
    __half* alinesT  = (__half*)(ws + 30188544);   // 3 * 4800 h      = 28,800 B

    hipMemsetAsync(ws, 0, 12544, stream);       // counter + rgbacc

    TPtrs tp;
    for (int i=0;i<3;i++) {
        tp.psrc[i]   = dplane[i]; tp.pdstf[i] = dplanesT + (size_t)i*PLANE_ELEMS;
        tp.psrc[3+i] = aplane[i]; tp.pdsth[i] = aplanesT + (size_t)i*PLANE_ELEMS;
        tp.lsrc[i]   = dline[i];  tp.ldstf[i] = dlinesT + i*(GRIDN*16);
        tp.lsrc[3+i] = aline[i];  tp.ldsth[i] = alinesT + i*(GRIDN*16);
    }
    dim3 tg((POS_ELEMS+255)/256, 6);
    hipLaunchKernelGGL(k_transpose, tg, dim3(256), 0, stream, tp);

    k_density<<<NRAYS, NSAMP, 0, stream>>>(
        ro, rd,
        dplanesT + 0*(size_t)PLANE_ELEMS, dplanesT + 1*(size_t)PLANE_ELEMS, dplanesT + 2*(size_t)PLANE_ELEMS,
        dlinesT + 0*(GRIDN*16), dlinesT + 1*(GRIDN*16), dlinesT + 2*(GRIDN*16),
        weights, accb, out + NRAYS*3, list, counter);

    k_mlp<<<512, 512, 0, stream>>>(
        ro, rd,
        aplanesT + 0*(size_t)PLANE_ELEMS, aplanesT + 1*(size_t)PLANE_ELEMS, aplanesT + 2*(size_t)PLANE_ELEMS,
        alinesT + 0*(GRIDN*16), alinesT + 1*(GRIDN*16), alinesT + 2*(GRIDN*16),
        basis_w, w1, b1, w2, b2, w3, b3,
        weights, list, counter, rgbacc);

    k_final<<<(NRAYS*3+255)/256, 256, 0, stream>>>(rgbacc, accb, out);
}

// Round 6
// 222.837 us; speedup vs baseline: 1.8017x; 1.0444x over previous
//
#include <hip/hip_runtime.h>
#include <hip/hip_fp16.h>
#include <math.h>

#define NRAYS 1024
#define NSAMP 512
#define GRIDN 300
#define POS_ELEMS (GRIDN*GRIDN)
#define PLANE_ELEMS (16*POS_ELEMS)

typedef short bf16x8 __attribute__((ext_vector_type(8)));
typedef float f32x4  __attribute__((ext_vector_type(4)));

struct H8v { __half2 h[4]; };    // 8 fp16 = 16B

__device__ __forceinline__ float clampf(float x, float a, float b){ return fminf(fmaxf(x,a),b); }
__device__ __forceinline__ unsigned short f2b(float f){
    unsigned u = __builtin_bit_cast(unsigned, f);
    u = (u + 0x7FFFu + ((u>>16)&1u)) >> 16;
    return (unsigned short)u;
}
__device__ __forceinline__ float b2f(unsigned short h){
    unsigned u = ((unsigned)h) << 16;
    return __builtin_bit_cast(float, u);
}

// ---------------------------------------------------------------- transpose: all -> channel-last fp16
struct TPtrs {
    const float* psrc[6]; __half* pdst[6];
    const float* lsrc[6]; __half* ldst[6];
};

__global__ __launch_bounds__(256) void k_transpose(TPtrs tp) {
    int by  = blockIdx.y;
    int pos = blockIdx.x * 256 + threadIdx.x;
    if (pos < POS_ELEMS) {
        const float* src = tp.psrc[by];
        __half2 o[8];
        #pragma unroll
        for (int e = 0; e < 8; e++) {
            float a = src[(2*e  ) * POS_ELEMS + pos];
            float b = src[(2*e+1) * POS_ELEMS + pos];
            o[e] = __float22half2_rn(make_float2(a,b));
        }
        float4* dst = (float4*)(tp.pdst[by] + (size_t)pos * 16);
        dst[0] = *(float4*)&o[0];
        dst[1] = *(float4*)&o[4];
    }
    if (pos < GRIDN) {
        const float* ls = tp.lsrc[by];
        __half*      ld = tp.ldst[by];
        #pragma unroll
        for (int c = 0; c < 16; c++) ld[pos * 16 + c] = __float2half_rn(ls[c * GRIDN + pos]);
    }
}

// ---------------------------------------------------------------- density + weights (fp16 storage, f32 math)
__global__ __launch_bounds__(512) void k_density(
    const float* __restrict__ ro, const float* __restrict__ rd,
    const __half* __restrict__ dpT0, const __half* __restrict__ dpT1, const __half* __restrict__ dpT2,
    const __half* __restrict__ dlT0, const __half* __restrict__ dlT1, const __half* __restrict__ dlT2,
    float* __restrict__ weights, float* __restrict__ acc_out, float* __restrict__ depth_out,
    int* __restrict__ list, int* __restrict__ counter)
{
    const float STEPF = (3.0f/299.0f)*0.5f;
    int r = blockIdx.x;
    int s = threadIdx.x;
    int lane = s & 63, wv = s >> 6;

    float o0=ro[r*3+0], o1=ro[r*3+1], o2=ro[r*3+2];
    float d0=rd[r*3+0], d1=rd[r*3+1], d2=rd[r*3+2];

    float t_min = -1e30f;
    {
        float v0=(d0==0.f)?1e-6f:d0, v1=(d1==0.f)?1e-6f:d1, v2=(d2==0.f)?1e-6f:d2;
        float a,b;
        a=(1.5f-o0)/v0; b=(-1.5f-o0)/v0; t_min=fmaxf(t_min,fminf(a,b));
        a=(1.5f-o1)/v1; b=(-1.5f-o1)/v1; t_min=fmaxf(t_min,fminf(a,b));
        a=(1.5f-o2)/v2; b=(-1.5f-o2)/v2; t_min=fmaxf(t_min,fminf(a,b));
        t_min = clampf(t_min, 2.0f, 6.0f);
    }
    float z  = t_min + STEPF * (float)s;
    float p0 = o0 + d0*z, p1 = o1 + d1*z, p2 = o2 + d2*z;
    bool valid = (p0>=-1.5f)&&(p0<=1.5f)&&(p1>=-1.5f)&&(p1<=1.5f)&&(p2>=-1.5f)&&(p2<=1.5f);

    float sig = 0.f;
    if (valid) {
        float xn[3] = { (p0+1.5f)*(2.0f/3.0f)-1.0f,
                        (p1+1.5f)*(2.0f/3.0f)-1.0f,
                        (p2+1.5f)*(2.0f/3.0f)-1.0f };
        const __half* dpT[3] = {dpT0,dpT1,dpT2};
        const __half* dlT[3] = {dlT0,dlT1,dlT2};
        const int M0[3]={0,0,1}, M1[3]={1,2,2}, V[3]={2,1,0};
        float sf = 0.f;
        #pragma unroll
        for (int i=0;i<3;i++) {
            float fx = clampf((xn[M0[i]]*0.5f+0.5f)*299.f, 0.f, 299.f);
            float fy = clampf((xn[M1[i]]*0.5f+0.5f)*299.f, 0.f, 299.f);
            float ft = clampf((xn[V[i]] *0.5f+0.5f)*299.f, 0.f, 299.f);
            int x0=min((int)fx,298), y0=min((int)fy,298), i0=min((int)ft,298);
            float wx=fx-(float)x0, wy=fy-(float)y0, wt=ft-(float)i0;
            // 64B contiguous per row: (x0, x0+1) x 16ch fp16
            const H8v* r0 = (const H8v*)(dpT[i] + (size_t)( y0   *GRIDN+x0)*16);
            const H8v* r1 = (const H8v*)(dpT[i] + (size_t)((y0+1)*GRIDN+x0)*16);
            const H8v* lp = (const H8v*)(dlT[i] + (size_t)i0*16);
            H8v a0[4] = {r0[0],r0[1],r0[2],r0[3]};   // [0,1]=x0 ch0-15, [2,3]=x0+1 ch0-15
            H8v a1[4] = {r1[0],r1[1],r1[2],r1[3]};
            H8v lv[4] = {lp[0],lp[1],lp[2],lp[3]};   // [0,1]=i0, [2,3]=i0+1
            #pragma unroll
            for (int cb=0; cb<2; cb++) {
                #pragma unroll
                for (int e=0; e<4; e++) {
                    float2 c00 = __half22float2(a0[cb  ].h[e]);
                    float2 c01 = __half22float2(a0[cb+2].h[e]);
                    float2 c10 = __half22float2(a1[cb  ].h[e]);
                    float2 c11 = __half22float2(a1[cb+2].h[e]);
                    float2 l0  = __half22float2(lv[cb  ].h[e]);
                    float2 l1  = __half22float2(lv[cb+2].h[e]);
                    float bx = (c00.x*(1.f-wx)+c01.x*wx)*(1.f-wy) + (c10.x*(1.f-wx)+c11.x*wx)*wy;
                    float by = (c00.y*(1.f-wx)+c01.y*wx)*(1.f-wy) + (c10.y*(1.f-wx)+c11.y*wx)*wy;
                    float lx = l0.x*(1.f-wt)+l1.x*wt;
                    float ly = l0.y*(1.f-wt)+l1.y*wt;
                    sf += bx*lx + by*ly;
                }
            }
        }
        float xs = sf - 10.0f;
        sig = fmaxf(xs, 0.f) + __logf(1.f + __expf(-fabsf(xs)));   // softplus
    }
    float alpha = (s < NSAMP-1) ? (1.f - __expf(-sig * (STEPF*25.0f))) : 0.f;

    // wave-level multiplicative inclusive scan of (1-alpha+eps)
    float v = (1.f - alpha) + 1e-10f;
    float inc = v;
    #pragma unroll
    for (int off=1; off<64; off<<=1) {
        float t = __shfl_up(inc, off, 64);
        if (lane >= off) inc *= t;
    }
    __shared__ float wtot[8], swsum[8], sdep[8];
    if (lane == 63) wtot[wv] = inc;
    __syncthreads();
    float pre = 1.f;
    for (int i=0;i<wv;i++) pre *= wtot[i];
    float excl = __shfl_up(inc, 1, 64);
    if (lane == 0) excl = 1.f;
    float T = pre * excl;
    float w = alpha * T;
    weights[r*NSAMP + s] = w;

    float rw = w, rz = w*z;
    #pragma unroll
    for (int off=32; off>0; off>>=1) { rw += __shfl_xor(rw,off,64); rz += __shfl_xor(rz,off,64); }
    if (lane == 0) { swsum[wv] = rw; sdep[wv] = rz; }
    __syncthreads();
    if (s == 0) {
        float a=0.f, b=0.f;
        #pragma unroll
        for (int i=0;i<8;i++){ a+=swsum[i]; b+=sdep[i]; }
        acc_out[r] = a; depth_out[r] = b;
    }

    bool act = (w > 1e-4f);
    unsigned long long m = __ballot(act);
    int cnt  = __popcll(m);
    if (cnt) {
        int base = 0;
        if (lane==0) base = atomicAdd(counter, cnt);
        base = __shfl(base, 0);
        if (act) {
            int pofs = __popcll(m & ((1ull<<lane)-1ull));
            list[base + pofs] = (r<<9) | s;
        }
    }
}

// ---------------------------------------------------------------- masked appearance + MFMA MLP
#define XST 168   // bf16 row stride for X (21*16B -> bank-spread)
#define HST 136   // bf16 row stride for H1/H2 (17*16B)
#define CST 52    // f32 row stride for coefs

__global__ __launch_bounds__(512, 4) void k_mlp(
    const float* __restrict__ ro, const float* __restrict__ rd,
    const __half* __restrict__ apT0, const __half* __restrict__ apT1, const __half* __restrict__ apT2,
    const __half* __restrict__ alT0, const __half* __restrict__ alT1, const __half* __restrict__ alT2,
    const float* __restrict__ basis_w, const float* __restrict__ w1p, const float* __restrict__ b1p,
    const float* __restrict__ w2p, const float* __restrict__ b2p,
    const float* __restrict__ w3p, const float* __restrict__ b3p,
    const float* __restrict__ weights, const int* __restrict__ list, const int* __restrict__ counter,
    float* __restrict__ rgbacc)
{
    __shared__ __align__(16) unsigned short Xs[64*XST];   // X (bf16), later H2 (stride HST)
    __shared__ __align__(16) unsigned short Hs[64*HST];   // H1
    __shared__ __align__(16) float Cs[64*CST];            // 48 appearance coefs per sample

    const float STEPF = (3.0f/299.0f)*0.5f;
    int tid  = threadIdx.x;
    int wvid = tid >> 6, lane = tid & 63, ln15 = lane & 15, kq = lane >> 4;

    // ---- weights -> VGPRs: wave wvid owns N-columns [16*wvid, 16*wvid+16)
    int jrow = (wvid<<4) + ln15;
    bf16x8 w1f[5], w2f[4];
    #pragma unroll
    for (int ks=0; ks<4; ks++) {
        int ko = ks*32 + kq*8;
        #pragma unroll
        for (int e=0;e<8;e++) w1f[ks][e] = (short)f2b(w1p[jrow*150 + ko + e]);
    }
    {
        int ko = 128 + kq*8;
        #pragma unroll
        for (int e=0;e<8;e++) {
            int k = ko + e;
            w1f[4][e] = (short)((k < 150) ? f2b(w1p[jrow*150 + k]) : 0);
        }
    }
    #pragma unroll
    for (int ks=0; ks<4; ks++) {
        int ko = ks*32 + kq*8;
        #pragma unroll
        for (int e=0;e<8;e++) w2f[ks][e] = (short)f2b(w2p[jrow*128 + ko + e]);
    }
    float bias1 = b1p[jrow];
    float bias2 = b2p[jrow];

    int count  = *counter;
    int ntiles = (count + 63) >> 6;

    for (int t = blockIdx.x; t < ntiles; t += gridDim.x) {
        // ---- P1: appearance gather (fp16) -> Cs
        {
            int u = tid >> 3, q = tid & 7;
            int idx = (t<<6) + u;
            if (q < 6) {
                int i = q >> 1, h = q & 1;
                if (idx < count) {
                    int sid = list[idx];
                    int r = sid >> 9, s = sid & (NSAMP-1);
                    float o0=ro[r*3+0], o1=ro[r*3+1], o2=ro[r*3+2];
                    float d0=rd[r*3+0], d1=rd[r*3+1], d2=rd[r*3+2];
                    float t_min = -1e30f;
                    float v0=(d0==0.f)?1e-6f:d0, v1=(d1==0.f)?1e-6f:d1, v2=(d2==0.f)?1e-6f:d2;
                    float a,b;
                    a=(1.5f-o0)/v0; b=(-1.5f-o0)/v0; t_min=fmaxf(t_min,fminf(a,b));
                    a=(1.5f-o1)/v1; b=(-1.5f-o1)/v1; t_min=fmaxf(t_min,fminf(a,b));
                    a=(1.5f-o2)/v2; b=(-1.5f-o2)/v2; t_min=fmaxf(t_min,fminf(a,b));
                    t_min = clampf(t_min, 2.0f, 6.0f);
                    float z = t_min + STEPF*(float)s;
                    float xn[3] = { ((o0+d0*z)+1.5f)*(2.0f/3.0f)-1.0f,
                                    ((o1+d1*z)+1.5f)*(2.0f/3.0f)-1.0f,
                                    ((o2+d2*z)+1.5f)*(2.0f/3.0f)-1.0f };
                    const __half* apT[3]={apT0,apT1,apT2};
                    const __half* alT[3]={alT0,alT1,alT2};
                    const int M0[3]={0,0,1}, M1[3]={1,2,2}, V[3]={2,1,0};
                    float fx = clampf((xn[M0[i]]*0.5f+0.5f)*299.f, 0.f, 299.f);
                    float fy = clampf((xn[M1[i]]*0.5f+0.5f)*299.f, 0.f, 299.f);
                    float ft = clampf((xn[V[i]] *0.5f+0.5f)*299.f, 0.f, 299.f);
                    int x0=min((int)fx,298), y0=min((int)fy,298), i0=min((int)ft,298);
                    float wx=fx-(float)x0, wy=fy-(float)y0, wt=ft-(float)i0;
                    __half2 w00=__float2half2_rn((1.f-wx)*(1.f-wy)), w01=__float2half2_rn(wx*(1.f-wy));
                    __half2 w10=__float2half2_rn((1.f-wx)*wy),       w11=__float2half2_rn(wx*wy);
                    __half2 u0 =__float2half2_rn(1.f-wt),            u1 =__float2half2_rn(wt);
                    const __half* base = apT[i] + (size_t)(y0*GRIDN+x0)*16 + h*8;
                    H8v a00 = *(const H8v*)(base);
                    H8v a01 = *(const H8v*)(base + 16);
                    H8v a10 = *(const H8v*)(base + GRIDN*16);
                    H8v a11 = *(const H8v*)(base + GRIDN*16 + 16);
                    const __half* lb = alT[i] + (size_t)i0*16 + h*8;
                    H8v l0 = *(const H8v*)(lb);
                    H8v l1 = *(const H8v*)(lb + 16);
                    float* C = &Cs[u*CST + i*16 + h*8];
                    #pragma unroll
                    for (int e=0;e<4;e++) {
                        __half2 p = __hmul2(a00.h[e],w00);
                        p = __hfma2(a01.h[e],w01,p);
                        p = __hfma2(a10.h[e],w10,p);
                        p = __hfma2(a11.h[e],w11,p);
                        __half2 l = __hmul2(l0.h[e],u0);
                        l = __hfma2(l1.h[e],u1,l);
                        float2 c = __half22float2(__hmul2(p,l));
                        C[2*e] = c.x; C[2*e+1] = c.y;
                    }
                } else {
                    float* C = &Cs[u*CST + i*16 + h*8];
                    #pragma unroll
                    for (int e=0;e<8;e++) C[e] = 0.f;
                }
            }
        }
        __syncthreads();

        // ---- P2: feat = basis @ coefs, posenc -> Xs (bf16)
        {
            int u = tid >> 3, q = tid & 7;
            unsigned short* X = Xs + u*XST;
            const float* C = Cs + u*CST;
            for (int j=q; j<27; j+=8) {
                float f = 0.f;
                const float* bwp = basis_w + j*48;
                #pragma unroll
                for (int k=0;k<48;k++) f += bwp[k]*C[k];
                X[j]      = f2b(f);
                X[30+2*j] = f2b(__sinf(f));     X[31+2*j] = f2b(__sinf(2.f*f));
                X[84+2*j] = f2b(__cosf(f));     X[85+2*j] = f2b(__cosf(2.f*f));
            }
            if (q == 7) {
                int idx = (t<<6) + u;
                float vd[3] = {0.f,0.f,0.f};
                if (idx < count) {
                    int r = list[idx] >> 9;
                    vd[0]=rd[r*3+0]; vd[1]=rd[r*3+1]; vd[2]=rd[r*3+2];
                }
                #pragma unroll
                for (int c=0;c<3;c++) {
                    float vv = vd[c];
                    X[27+c]     = f2b(vv);
                    X[138+2*c]  = f2b(__sinf(vv));  X[139+2*c] = f2b(__sinf(2.f*vv));
                    X[144+2*c]  = f2b(__cosf(vv));  X[145+2*c] = f2b(__cosf(2.f*vv));
                }
                #pragma unroll
                for (int k=150;k<XST;k++) X[k] = 0;   // k-pad
            }
        }
        __syncthreads();

        // ---- GEMM1 (MFMA): H1 = relu(X @ W1^T + b1); wave owns 16 cols, 4 M-tiles
        {
            f32x4 acc[4] = {};
            #pragma unroll
            for (int ks=0; ks<5; ks++) {
                int ko = ks*32 + kq*8;
                #pragma unroll
                for (int m=0;m<4;m++) {
                    bf16x8 a = *(const bf16x8*)&Xs[(m*16 + ln15)*XST + ko];
                    acc[m] = __builtin_amdgcn_mfma_f32_16x16x32_bf16(a, w1f[ks], acc[m], 0,0,0);
                }
            }
            int col = jrow;
            #pragma unroll
            for (int m=0;m<4;m++) {
                int rbase = m*16 + kq*4;
                #pragma unroll
                for (int j=0;j<4;j++)
                    Hs[(rbase+j)*HST + col] = f2b(fmaxf(acc[m][j] + bias1, 0.f));
            }
        }
        __syncthreads();

        // ---- GEMM2 (MFMA): H2 = relu(H1 @ W2^T + b2) -> Xs region (stride HST)
        {
            f32x4 acc[4] = {};
            #pragma unroll
            for (int ks=0; ks<4; ks++) {
                int ko = ks*32 + kq*8;
                #pragma unroll
                for (int m=0;m<4;m++) {
                    bf16x8 a = *(const bf16x8*)&Hs[(m*16 + ln15)*HST + ko];
                    acc[m] = __builtin_amdgcn_mfma_f32_16x16x32_bf16(a, w2f[ks], acc[m], 0,0,0);
                }
            }
            int col = jrow;
            #pragma unroll
            for (int m=0;m<4;m++) {
                int rbase = m*16 + kq*4;
                #pragma unroll
                for (int j=0;j<4;j++)
                    Xs[(rbase+j)*HST + col] = f2b(fmaxf(acc[m][j] + bias2, 0.f));
            }
        }
        __syncthreads();

        // ---- P5: rgb = sigmoid(H2 @ W3^T + b3); plain per-sample atomics
        if (tid < 256) {
            int u = tid >> 2, ch = tid & 3;
            int idx = (t<<6) + u;
            if (ch < 3 && idx < count) {
                int sid = list[idx];
                float wgt = weights[sid];
                if (wgt > 0.f) {
                    const unsigned short* h2 = Xs + u*HST;
                    const float* wr = w3p + ch*128;
                    float acc5 = b3p[ch];
                    #pragma unroll
                    for (int k=0;k<128;k+=8) {
                        bf16x8 hv = *(const bf16x8*)&h2[k];
                        #pragma unroll
                        for (int e=0;e<8;e++)
                            acc5 += b2f((unsigned short)hv[e]) * wr[k+e];
                    }
                    float rgbv = 1.f/(1.f + __expf(-acc5));
                    atomicAdd(&rgbacc[(sid>>9)*3 + ch], wgt*rgbv);
                }
            }
        }
        __syncthreads();   // protect Cs/Xs/Hs before next tile
    }
}

// ---------------------------------------------------------------- finalize rgb_map
__global__ __launch_bounds__(256) void k_final(
    const float* __restrict__ rgbacc, const float* __restrict__ acc_out, float* __restrict__ out)
{
    int i = blockIdx.x*256 + threadIdx.x;
    if (i < NRAYS*3) {
        int r = i/3;
        out[i] = clampf(rgbacc[i] + (1.f - acc_out[r]), 0.f, 1.f);
    }
}

// ---------------------------------------------------------------- launch
extern "C" void kernel_launch(void* const* d_in, const int* in_sizes, int n_in,
                              void* d_out, int out_size, void* d_ws, size_t ws_size,
                              hipStream_t stream)
{
    const float* ro = (const float*)d_in[0];
    const float* rd = (const float*)d_in[1];
    const float* dplane[3] = {(const float*)d_in[2],(const float*)d_in[6],(const float*)d_in[10]};
    const float* dline[3]  = {(const float*)d_in[3],(const float*)d_in[7],(const float*)d_in[11]};
    const float* aplane[3] = {(const float*)d_in[4],(const float*)d_in[8],(const float*)d_in[12]};
    const float* aline[3]  = {(const float*)d_in[5],(const float*)d_in[9],(const float*)d_in[13]};
    const float* basis_w = (const float*)d_in[14];
    const float* w1 = (const float*)d_in[15];
    const float* b1 = (const float*)d_in[16];
    const float* w2 = (const float*)d_in[17];
    const float* b2 = (const float*)d_in[18];
    const float* w3 = (const float*)d_in[19];
    const float* b3 = (const float*)d_in[20];
    float* out = (float*)d_out;

    char* ws = (char*)d_ws;
    int*    counter  = (int*)   (ws + 0);
    float*  rgbacc   = (float*) (ws + 256);        // 3072 f
    float*  accb     = (float*) (ws + 12544);      // 1024 f
    float*  weights  = (float*) (ws + 16640);      // 524288 f
    int*    list     = (int*)   (ws + 2113792);    // 524288 i
    __half* planesT  = (__half*)(ws + 4210944);    // 6 * 1,440,000 halfs = 17,280,000 B
    __half* linesT   = (__half*)(ws + 21490944);   // 6 * 4800 halfs = 57,600 B

    hipMemsetAsync(ws, 0, 12544, stream);       // counter + rgbacc

    TPtrs tp;
    for (int i=0;i<3;i++) {
        tp.psrc[i]   = dplane[i]; tp.pdst[i]   = planesT + (size_t)i*PLANE_ELEMS;
        tp.psrc[3+i] = aplane[i]; tp.pdst[3+i] = planesT + (size_t)(3+i)*PLANE_ELEMS;
        tp.lsrc[i]   = dline[i];  tp.ldst[i]   = linesT + i*(GRIDN*16);
        tp.lsrc[3+i] = aline[i];  tp.ldst[3+i] = linesT + (3+i)*(GRIDN*16);
    }
    dim3 tg((POS_ELEMS+255)/256, 6);
    hipLaunchKernelGGL(k_transpose, tg, dim3(256), 0, stream, tp);

    k_density<<<NRAYS, NSAMP, 0, stream>>>(
        ro, rd,
        planesT + 0*(size_t)PLANE_ELEMS, planesT + 1*(size_t)PLANE_ELEMS, planesT + 2*(size_t)PLANE_ELEMS,
        linesT + 0*(GRIDN*16), linesT + 1*(GRIDN*16), linesT + 2*(GRIDN*16),
        weights, accb, out + NRAYS*3, list, counter);

    k_mlp<<<512, 512, 0, stream>>>(
        ro, rd,
        planesT + 3*(size_t)PLANE_ELEMS, planesT + 4*(size_t)PLANE_ELEMS, planesT + 5*(size_t)PLANE_ELEMS,
        linesT + 3*(GRIDN*16), linesT + 4*(GRIDN*16), linesT + 5*(GRIDN*16),
        basis_w, w1, b1, w2, b2, w3, b3,
        weights, list, counter, rgbacc);

    k_final<<<(NRAYS*3+255)/256, 256, 0, stream>>>(rgbacc, accb, out);
}

// Round 7
// 174.233 us; speedup vs baseline: 2.3043x; 1.2790x over previous
//
#include <hip/hip_runtime.h>
#include <hip/hip_fp16.h>
#include <math.h>

#define NRAYS 1024
#define NSAMP 512
#define GRIDN 300
#define POS_ELEMS (GRIDN*GRIDN)
#define PLANE_ELEMS (16*POS_ELEMS)

typedef short bf16x8 __attribute__((ext_vector_type(8)));
typedef float f32x4  __attribute__((ext_vector_type(4)));

struct H8v { __half2 h[4]; };    // 8 fp16 = 16B

__device__ __forceinline__ float clampf(float x, float a, float b){ return fminf(fmaxf(x,a),b); }
__device__ __forceinline__ unsigned short f2b(float f){
    unsigned u = __builtin_bit_cast(unsigned, f);
    u = (u + 0x7FFFu + ((u>>16)&1u)) >> 16;
    return (unsigned short)u;
}
__device__ __forceinline__ float b2f(unsigned short h){
    unsigned u = ((unsigned)h) << 16;
    return __builtin_bit_cast(float, u);
}

// ---------------------------------------------------------------- transpose: all -> channel-last fp16
struct TPtrs {
    const float* psrc[6]; __half* pdst[6];
    const float* lsrc[6]; __half* ldst[6];
};

__global__ __launch_bounds__(256) void k_transpose(TPtrs tp) {
    int by  = blockIdx.y;
    int pos = blockIdx.x * 256 + threadIdx.x;
    if (pos < POS_ELEMS) {
        const float* src = tp.psrc[by];
        __half2 o[8];
        #pragma unroll
        for (int e = 0; e < 8; e++) {
            float a = src[(2*e  ) * POS_ELEMS + pos];
            float b = src[(2*e+1) * POS_ELEMS + pos];
            o[e] = __float22half2_rn(make_float2(a,b));
        }
        float4* dst = (float4*)(tp.pdst[by] + (size_t)pos * 16);
        dst[0] = *(float4*)&o[0];
        dst[1] = *(float4*)&o[4];
    }
    if (pos < GRIDN) {
        const float* ls = tp.lsrc[by];
        __half*      ld = tp.ldst[by];
        #pragma unroll
        for (int c = 0; c < 16; c++) ld[pos * 16 + c] = __float2half_rn(ls[c * GRIDN + pos]);
    }
}

// ---------------------------------------------------------------- density gather helper (fp16 storage, f32 math)
__device__ __forceinline__ float density_feat(
    const __half* __restrict__ dpT0, const __half* __restrict__ dpT1, const __half* __restrict__ dpT2,
    const __half* __restrict__ dlT0, const __half* __restrict__ dlT1, const __half* __restrict__ dlT2,
    const float xn[3])
{
    const __half* dpT[3] = {dpT0,dpT1,dpT2};
    const __half* dlT[3] = {dlT0,dlT1,dlT2};
    const int M0[3]={0,0,1}, M1[3]={1,2,2}, V[3]={2,1,0};
    float sf = 0.f;
    #pragma unroll
    for (int i=0;i<3;i++) {
        float fx = clampf((xn[M0[i]]*0.5f+0.5f)*299.f, 0.f, 299.f);
        float fy = clampf((xn[M1[i]]*0.5f+0.5f)*299.f, 0.f, 299.f);
        float ft = clampf((xn[V[i]] *0.5f+0.5f)*299.f, 0.f, 299.f);
        int x0=min((int)fx,298), y0=min((int)fy,298), i0=min((int)ft,298);
        float wx=fx-(float)x0, wy=fy-(float)y0, wt=ft-(float)i0;
        const H8v* r0 = (const H8v*)(dpT[i] + (size_t)( y0   *GRIDN+x0)*16);
        const H8v* r1 = (const H8v*)(dpT[i] + (size_t)((y0+1)*GRIDN+x0)*16);
        const H8v* lp = (const H8v*)(dlT[i] + (size_t)i0*16);
        H8v a0[4] = {r0[0],r0[1],r0[2],r0[3]};   // [0,1]=x0 ch0-15, [2,3]=x0+1 ch0-15
        H8v a1[4] = {r1[0],r1[1],r1[2],r1[3]};
        H8v lv[4] = {lp[0],lp[1],lp[2],lp[3]};   // [0,1]=i0, [2,3]=i0+1
        #pragma unroll
        for (int cb=0; cb<2; cb++) {
            #pragma unroll
            for (int e=0; e<4; e++) {
                float2 c00 = __half22float2(a0[cb  ].h[e]);
                float2 c01 = __half22float2(a0[cb+2].h[e]);
                float2 c10 = __half22float2(a1[cb  ].h[e]);
                float2 c11 = __half22float2(a1[cb+2].h[e]);
                float2 l0  = __half22float2(lv[cb  ].h[e]);
                float2 l1  = __half22float2(lv[cb+2].h[e]);
                float bx = (c00.x*(1.f-wx)+c01.x*wx)*(1.f-wy) + (c10.x*(1.f-wx)+c11.x*wx)*wy;
                float by = (c00.y*(1.f-wx)+c01.y*wx)*(1.f-wy) + (c10.y*(1.f-wx)+c11.y*wx)*wy;
                float lx = l0.x*(1.f-wt)+l1.x*wt;
                float ly = l0.y*(1.f-wt)+l1.y*wt;
                sf += bx*lx + by*ly;
            }
        }
    }
    return sf;
}

// ---------------------------------------------------------------- density + weights
// 256 threads/ray; thread owns samples 2*tid and 2*tid+1 (2x MLP vs 1 sample/thread)
__global__ __launch_bounds__(256) void k_density(
    const float* __restrict__ ro, const float* __restrict__ rd,
    const __half* __restrict__ dpT0, const __half* __restrict__ dpT1, const __half* __restrict__ dpT2,
    const __half* __restrict__ dlT0, const __half* __restrict__ dlT1, const __half* __restrict__ dlT2,
    float* __restrict__ weights, float* __restrict__ acc_out, float* __restrict__ depth_out,
    int* __restrict__ list, int* __restrict__ counter)
{
    const float STEPF = (3.0f/299.0f)*0.5f;
    int r = blockIdx.x;
    int tid = threadIdx.x;
    int lane = tid & 63, wv = tid >> 6;

    float o0=ro[r*3+0], o1=ro[r*3+1], o2=ro[r*3+2];
    float d0=rd[r*3+0], d1=rd[r*3+1], d2=rd[r*3+2];

    float t_min = -1e30f;
    {
        float v0=(d0==0.f)?1e-6f:d0, v1=(d1==0.f)?1e-6f:d1, v2=(d2==0.f)?1e-6f:d2;
        float a,b;
        a=(1.5f-o0)/v0; b=(-1.5f-o0)/v0; t_min=fmaxf(t_min,fminf(a,b));
        a=(1.5f-o1)/v1; b=(-1.5f-o1)/v1; t_min=fmaxf(t_min,fminf(a,b));
        a=(1.5f-o2)/v2; b=(-1.5f-o2)/v2; t_min=fmaxf(t_min,fminf(a,b));
        t_min = clampf(t_min, 2.0f, 6.0f);
    }

    float zj[2], aj[2];
    #pragma unroll
    for (int j=0;j<2;j++) {
        int s = 2*tid + j;
        float z = t_min + STEPF * (float)s;
        zj[j] = z;
        float p0 = o0 + d0*z, p1 = o1 + d1*z, p2 = o2 + d2*z;
        bool valid = (p0>=-1.5f)&&(p0<=1.5f)&&(p1>=-1.5f)&&(p1<=1.5f)&&(p2>=-1.5f)&&(p2<=1.5f);
        float sig = 0.f;
        if (valid) {
            float xn[3] = { (p0+1.5f)*(2.0f/3.0f)-1.0f,
                            (p1+1.5f)*(2.0f/3.0f)-1.0f,
                            (p2+1.5f)*(2.0f/3.0f)-1.0f };
            float sf = density_feat(dpT0,dpT1,dpT2,dlT0,dlT1,dlT2,xn);
            float xs = sf - 10.0f;
            sig = fmaxf(xs, 0.f) + __logf(1.f + __expf(-fabsf(xs)));   // softplus
        }
        aj[j] = (s < NSAMP-1) ? (1.f - __expf(-sig * (STEPF*25.0f))) : 0.f;
    }

    // pair-product wave scan of (1-alpha+eps)
    float v0 = (1.f - aj[0]) + 1e-10f;
    float v1 = (1.f - aj[1]) + 1e-10f;
    float pair = v0 * v1;
    float inc = pair;
    #pragma unroll
    for (int off=1; off<64; off<<=1) {
        float t = __shfl_up(inc, off, 64);
        if (lane >= off) inc *= t;
    }
    __shared__ float wtot[4], swsum[4], sdep[4];
    if (lane == 63) wtot[wv] = inc;
    __syncthreads();
    float pre = 1.f;
    for (int i=0;i<wv;i++) pre *= wtot[i];
    float excl = __shfl_up(inc, 1, 64);
    if (lane == 0) excl = 1.f;
    float T0 = pre * excl;                 // transmittance before sample 2*tid
    float w0 = aj[0] * T0;
    float w1 = aj[1] * T0 * v0;
    weights[r*NSAMP + 2*tid    ] = w0;
    weights[r*NSAMP + 2*tid + 1] = w1;

    // fused reductions: sum(w), sum(w*z)
    float rw = w0 + w1, rz = w0*zj[0] + w1*zj[1];
    #pragma unroll
    for (int off=32; off>0; off>>=1) { rw += __shfl_xor(rw,off,64); rz += __shfl_xor(rz,off,64); }
    if (lane == 0) { swsum[wv] = rw; sdep[wv] = rz; }
    __syncthreads();
    if (tid == 0) {
        float a=0.f, b=0.f;
        #pragma unroll
        for (int i=0;i<4;i++){ a+=swsum[i]; b+=sdep[i]; }
        acc_out[r] = a; depth_out[r] = b;
    }

    // wave-aggregated compaction (two samples per lane, ascending in-wave order)
    bool act0 = (w0 > 1e-4f), act1 = (w1 > 1e-4f);
    unsigned long long m0 = __ballot(act0);
    unsigned long long m1 = __ballot(act1);
    int tot = __popcll(m0) + __popcll(m1);
    if (tot) {
        int base = 0;
        if (lane==0) base = atomicAdd(counter, tot);
        base = __shfl(base, 0);
        unsigned long long below = (1ull<<lane)-1ull;
        int pofs = __popcll(m0 & below) + __popcll(m1 & below);
        if (act0) list[base + pofs]              = (r<<9) | (2*tid);
        if (act1) list[base + pofs + (act0?1:0)] = (r<<9) | (2*tid+1);
    }
}

// ---------------------------------------------------------------- masked appearance + MFMA MLP
#define XST 168   // bf16 row stride for X (21*16B -> bank-spread)
#define HST 136   // bf16 row stride for H1/H2 (17*16B)
#define CST 52    // f32 row stride for coefs

__global__ __launch_bounds__(512, 4) void k_mlp(
    const float* __restrict__ ro, const float* __restrict__ rd,
    const __half* __restrict__ apT0, const __half* __restrict__ apT1, const __half* __restrict__ apT2,
    const __half* __restrict__ alT0, const __half* __restrict__ alT1, const __half* __restrict__ alT2,
    const float* __restrict__ basis_w, const float* __restrict__ w1p, const float* __restrict__ b1p,
    const float* __restrict__ w2p, const float* __restrict__ b2p,
    const float* __restrict__ w3p, const float* __restrict__ b3p,
    const float* __restrict__ weights, const int* __restrict__ list, const int* __restrict__ counter,
    float* __restrict__ rgbacc)
{
    __shared__ __align__(16) unsigned short Xs[64*XST];   // X (bf16), later H2 (stride HST)
    __shared__ __align__(16) unsigned short Hs[64*HST];   // H1
    __shared__ __align__(16) float Cs[64*CST];            // 48 appearance coefs per sample

    const float STEPF = (3.0f/299.0f)*0.5f;
    int tid  = threadIdx.x;
    int wvid = tid >> 6, lane = tid & 63, ln15 = lane & 15, kq = lane >> 4;

    // ---- weights -> VGPRs: wave wvid owns N-columns [16*wvid, 16*wvid+16)
    int jrow = (wvid<<4) + ln15;
    bf16x8 w1f[5], w2f[4];
    #pragma unroll
    for (int ks=0; ks<4; ks++) {
        int ko = ks*32 + kq*8;
        #pragma unroll
        for (int e=0;e<8;e++) w1f[ks][e] = (short)f2b(w1p[jrow*150 + ko + e]);
    }
    {
        int ko = 128 + kq*8;
        #pragma unroll
        for (int e=0;e<8;e++) {
            int k = ko + e;
            w1f[4][e] = (short)((k < 150) ? f2b(w1p[jrow*150 + k]) : 0);
        }
    }
    #pragma unroll
    for (int ks=0; ks<4; ks++) {
        int ko = ks*32 + kq*8;
        #pragma unroll
        for (int e=0;e<8;e++) w2f[ks][e] = (short)f2b(w2p[jrow*128 + ko + e]);
    }
    float bias1 = b1p[jrow];
    float bias2 = b2p[jrow];

    int count  = *counter;
    int ntiles = (count + 63) >> 6;

    for (int t = blockIdx.x; t < ntiles; t += gridDim.x) {
        // ---- P1: appearance gather (fp16) -> Cs
        {
            int u = tid >> 3, q = tid & 7;
            int idx = (t<<6) + u;
            if (q < 6) {
                int i = q >> 1, h = q & 1;
                if (idx < count) {
                    int sid = list[idx];
                    int r = sid >> 9, s = sid & (NSAMP-1);
                    float o0=ro[r*3+0], o1=ro[r*3+1], o2=ro[r*3+2];
                    float d0=rd[r*3+0], d1=rd[r*3+1], d2=rd[r*3+2];
                    float t_min = -1e30f;
                    float v0=(d0==0.f)?1e-6f:d0, v1=(d1==0.f)?1e-6f:d1, v2=(d2==0.f)?1e-6f:d2;
                    float a,b;
                    a=(1.5f-o0)/v0; b=(-1.5f-o0)/v0; t_min=fmaxf(t_min,fminf(a,b));
                    a=(1.5f-o1)/v1; b=(-1.5f-o1)/v1; t_min=fmaxf(t_min,fminf(a,b));
                    a=(1.5f-o2)/v2; b=(-1.5f-o2)/v2; t_min=fmaxf(t_min,fminf(a,b));
                    t_min = clampf(t_min, 2.0f, 6.0f);
                    float z = t_min + STEPF*(float)s;
                    float xn[3] = { ((o0+d0*z)+1.5f)*(2.0f/3.0f)-1.0f,
                                    ((o1+d1*z)+1.5f)*(2.0f/3.0f)-1.0f,
                                    ((o2+d2*z)+1.5f)*(2.0f/3.0f)-1.0f };
                    const __half* apT[3]={apT0,apT1,apT2};
                    const __half* alT[3]={alT0,alT1,alT2};
                    const int M0[3]={0,0,1}, M1[3]={1,2,2}, V[3]={2,1,0};
                    float fx = clampf((xn[M0[i]]*0.5f+0.5f)*299.f, 0.f, 299.f);
                    float fy = clampf((xn[M1[i]]*0.5f+0.5f)*299.f, 0.f, 299.f);
                    float ft = clampf((xn[V[i]] *0.5f+0.5f)*299.f, 0.f, 299.f);
                    int x0=min((int)fx,298), y0=min((int)fy,298), i0=min((int)ft,298);
                    float wx=fx-(float)x0, wy=fy-(float)y0, wt=ft-(float)i0;
                    __half2 w00=__float2half2_rn((1.f-wx)*(1.f-wy)), w01=__float2half2_rn(wx*(1.f-wy));
                    __half2 w10=__float2half2_rn((1.f-wx)*wy),       w11=__float2half2_rn(wx*wy);
                    __half2 u0 =__float2half2_rn(1.f-wt),            u1 =__float2half2_rn(wt);
                    const __half* base = apT[i] + (size_t)(y0*GRIDN+x0)*16 + h*8;
                    H8v a00 = *(const H8v*)(base);
                    H8v a01 = *(const H8v*)(base + 16);
                    H8v a10 = *(const H8v*)(base + GRIDN*16);
                    H8v a11 = *(const H8v*)(base + GRIDN*16 + 16);
                    const __half* lb = alT[i] + (size_t)i0*16 + h*8;
                    H8v l0 = *(const H8v*)(lb);
                    H8v l1 = *(const H8v*)(lb + 16);
                    float* C = &Cs[u*CST + i*16 + h*8];
                    #pragma unroll
                    for (int e=0;e<4;e++) {
                        __half2 p = __hmul2(a00.h[e],w00);
                        p = __hfma2(a01.h[e],w01,p);
                        p = __hfma2(a10.h[e],w10,p);
                        p = __hfma2(a11.h[e],w11,p);
                        __half2 l = __hmul2(l0.h[e],u0);
                        l = __hfma2(l1.h[e],u1,l);
                        float2 c = __half22float2(__hmul2(p,l));
                        C[2*e] = c.x; C[2*e+1] = c.y;
                    }
                } else {
                    float* C = &Cs[u*CST + i*16 + h*8];
                    #pragma unroll
                    for (int e=0;e<8;e++) C[e] = 0.f;
                }
            }
        }
        __syncthreads();

        // ---- P2: feat = basis @ coefs, posenc -> Xs (bf16)
        {
            int u = tid >> 3, q = tid & 7;
            unsigned short* X = Xs + u*XST;
            const float* C = Cs + u*CST;
            for (int j=q; j<27; j+=8) {
                float f = 0.f;
                const float* bwp = basis_w + j*48;
                #pragma unroll
                for (int k=0;k<48;k++) f += bwp[k]*C[k];
                X[j]      = f2b(f);
                X[30+2*j] = f2b(__sinf(f));     X[31+2*j] = f2b(__sinf(2.f*f));
                X[84+2*j] = f2b(__cosf(f));     X[85+2*j] = f2b(__cosf(2.f*f));
            }
            if (q == 7) {
                int idx = (t<<6) + u;
                float vd[3] = {0.f,0.f,0.f};
                if (idx < count) {
                    int r = list[idx] >> 9;
                    vd[0]=rd[r*3+0]; vd[1]=rd[r*3+1]; vd[2]=rd[r*3+2];
                }
                #pragma unroll
                for (int c=0;c<3;c++) {
                    float vv = vd[c];
                    X[27+c]     = f2b(vv);
                    X[138+2*c]  = f2b(__sinf(vv));  X[139+2*c] = f2b(__sinf(2.f*vv));
                    X[144+2*c]  = f2b(__cosf(vv));  X[145+2*c] = f2b(__cosf(2.f*vv));
                }
                #pragma unroll
                for (int k=150;k<XST;k++) X[k] = 0;   // k-pad
            }
        }
        __syncthreads();

        // ---- GEMM1 (MFMA): H1 = relu(X @ W1^T + b1); wave owns 16 cols, 4 M-tiles
        {
            f32x4 acc[4] = {};
            #pragma unroll
            for (int ks=0; ks<5; ks++) {
                int ko = ks*32 + kq*8;
                #pragma unroll
                for (int m=0;m<4;m++) {
                    bf16x8 a = *(const bf16x8*)&Xs[(m*16 + ln15)*XST + ko];
                    acc[m] = __builtin_amdgcn_mfma_f32_16x16x32_bf16(a, w1f[ks], acc[m], 0,0,0);
                }
            }
            int col = jrow;
            #pragma unroll
            for (int m=0;m<4;m++) {
                int rbase = m*16 + kq*4;
                #pragma unroll
                for (int j=0;j<4;j++)
                    Hs[(rbase+j)*HST + col] = f2b(fmaxf(acc[m][j] + bias1, 0.f));
            }
        }
        __syncthreads();

        // ---- GEMM2 (MFMA): H2 = relu(H1 @ W2^T + b2) -> Xs region (stride HST)
        {
            f32x4 acc[4] = {};
            #pragma unroll
            for (int ks=0; ks<4; ks++) {
                int ko = ks*32 + kq*8;
                #pragma unroll
                for (int m=0;m<4;m++) {
                    bf16x8 a = *(const bf16x8*)&Hs[(m*16 + ln15)*HST + ko];
                    acc[m] = __builtin_amdgcn_mfma_f32_16x16x32_bf16(a, w2f[ks], acc[m], 0,0,0);
                }
            }
            int col = jrow;
            #pragma unroll
            for (int m=0;m<4;m++) {
                int rbase = m*16 + kq*4;
                #pragma unroll
                for (int j=0;j<4;j++)
                    Xs[(rbase+j)*HST + col] = f2b(fmaxf(acc[m][j] + bias2, 0.f));
            }
        }
        __syncthreads();

        // ---- P5: rgb = sigmoid(H2 @ W3^T + b3); plain per-sample atomics
        if (tid < 256) {
            int u = tid >> 2, ch = tid & 3;
            int idx = (t<<6) + u;
            if (ch < 3 && idx < count) {
                int sid = list[idx];
                float wgt = weights[sid];
                if (wgt > 0.f) {
                    const unsigned short* h2 = Xs + u*HST;
                    const float* wr = w3p + ch*128;
                    float acc5 = b3p[ch];
                    #pragma unroll
                    for (int k=0;k<128;k+=8) {
                        bf16x8 hv = *(const bf16x8*)&h2[k];
                        #pragma unroll
                        for (int e=0;e<8;e++)
                            acc5 += b2f((unsigned short)hv[e]) * wr[k+e];
                    }
                    float rgbv = 1.f/(1.f + __expf(-acc5));
                    atomicAdd(&rgbacc[(sid>>9)*3 + ch], wgt*rgbv);
                }
            }
        }
        __syncthreads();   // protect Cs/Xs/Hs before next tile
    }
}

// ---------------------------------------------------------------- finalize rgb_map
__global__ __launch_bounds__(256) void k_final(
    const float* __restrict__ rgbacc, const float* __restrict__ acc_out, float* __restrict__ out)
{
    int i = blockIdx.x*256 + threadIdx.x;
    if (i < NRAYS*3) {
        int r = i/3;
        out[i] = clampf(rgbacc[i] + (1.f - acc_out[r]), 0.f, 1.f);
    }
}

// ---------------------------------------------------------------- launch
extern "C" void kernel_launch(void* const* d_in, const int* in_sizes, int n_in,
                              void* d_out, int out_size, void* d_ws, size_t ws_size,
                              hipStream_t stream)
{
    const float* ro = (const float*)d_in[0];
    const float* rd = (const float*)d_in[1];
    const float* dplane[3] = {(const float*)d_in[2],(const float*)d_in[6],(const float*)d_in[10]};
    const float* dline[3]  = {(const float*)d_in[3],(const float*)d_in[7],(const float*)d_in[11]};
    const float* aplane[3] = {(const float*)d_in[4],(const float*)d_in[8],(const float*)d_in[12]};
    const float* aline[3]  = {(const float*)d_in[5],(const float*)d_in[9],(const float*)d_in[13]};
    const float* basis_w = (const float*)d_in[14];
    const float* w1 = (const float*)d_in[15];
    const float* b1 = (const float*)d_in[16];
    const float* w2 = (const float*)d_in[17];
    const float* b2 = (const float*)d_in[18];
    const float* w3 = (const float*)d_in[19];
    const float* b3 = (const float*)d_in[20];
    float* out = (float*)d_out;

    char* ws = (char*)d_ws;
    int*    counter  = (int*)   (ws + 0);
    float*  rgbacc   = (float*) (ws + 256);        // 3072 f
    float*  accb     = (float*) (ws + 12544);      // 1024 f
    float*  weights  = (float*) (ws + 16640);      // 524288 f
    int*    list     = (int*)   (ws + 2113792);    // 524288 i
    __half* planesT  = (__half*)(ws + 4210944);    // 6 * 1,440,000 halfs = 17,280,000 B
    __half* linesT   = (__half*)(ws + 21490944);   // 6 * 4800 halfs = 57,600 B

    hipMemsetAsync(ws, 0, 12544, stream);       // counter + rgbacc

    TPtrs tp;
    for (int i=0;i<3;i++) {
        tp.psrc[i]   = dplane[i]; tp.pdst[i]   = planesT + (size_t)i*PLANE_ELEMS;
        tp.psrc[3+i] = aplane[i]; tp.pdst[3+i] = planesT + (size_t)(3+i)*PLANE_ELEMS;
        tp.lsrc[i]   = dline[i];  tp.ldst[i]   = linesT + i*(GRIDN*16);
        tp.lsrc[3+i] = aline[i];  tp.ldst[3+i] = linesT + (3+i)*(GRIDN*16);
    }
    dim3 tg((POS_ELEMS+255)/256, 6);
    hipLaunchKernelGGL(k_transpose, tg, dim3(256), 0, stream, tp);

    k_density<<<NRAYS, 256, 0, stream>>>(
        ro, rd,
        planesT + 0*(size_t)PLANE_ELEMS, planesT + 1*(size_t)PLANE_ELEMS, planesT + 2*(size_t)PLANE_ELEMS,
        linesT + 0*(GRIDN*16), linesT + 1*(GRIDN*16), linesT + 2*(GRIDN*16),
        weights, accb, out + NRAYS*3, list, counter);

    k_mlp<<<512, 512, 0, stream>>>(
        ro, rd,
        planesT + 3*(size_t)PLANE_ELEMS, planesT + 4*(size_t)PLANE_ELEMS, planesT + 5*(size_t)PLANE_ELEMS,
        linesT + 3*(GRIDN*16), linesT + 4*(GRIDN*16), linesT + 5*(GRIDN*16),
        basis_w, w1, b1, w2, b2, w3, b3,
        weights, list, counter, rgbacc);

    k_final<<<(NRAYS*3+255)/256, 256, 0, stream>>>(rgbacc, accb, out);
}